// Round 1
// baseline (330.029 us; speedup 1.0000x reference)
//
#include <hip/hip_runtime.h>
#include <math.h>

// ConvolutionalCapsule with EM routing, fully fused: one block per output
// position (b,ho,wo). Votes V[i,c,d] (288x32x16 per position) are NEVER
// materialized: recomputed from LDS patch tile + L2-resident W each pass.
// Key algebraic facts used:
//  - reference stdv uses Rsum (not Rw) => var = unweighted sum_i (v-M)^2,
//    so S1=sum_i v, S2=sum_i v^2 are iteration-invariant (computed once).
//  - E-step softmax is over the 32 output caps => in-register half-wave
//    shuffle reduction; R is never stored (fused E+M pass).
//  - cost = rsum * (16*beta_v + sum_d log(stdv+eps)) => stats needs only ONE
//    d-reduction (slog).
// This revision (vs 512-thread version):
//  - 1024 threads/block, IPT=9: 4.5 waves/SIMD avg (was 2.25), halved
//    per-pass serial path. Latency-bound kernel => occupancy is the lever.
//  - stats arrays padded to stride 17: LDS atomics are bank-conflict-free
//    ((17c+d) mod 32 is a bijection over c; was 16-way conflicted).
//  - stats phase parallelized over 512 threads (one per (c,d), shuffle
//    reduce over d) + tiny 32-thread cross-capsule tail.
//  - j-loops fully unrolled so the scheduler hoists W loads across
//    iterations; fast rcp in softmax/stat divides.
// Thread map: t = isub*32 + c. Half-wave (32 lanes) shares one input-capsule
// index i (broadcast LDS reads, contiguous 2KB W row reads), lanes span c.

#define EPSF 1e-7f
#define KKI 288
#define NC 32
#define NTHREADS 1024
#define NSUB 32        // NTHREADS/32
#define IPT 9          // KKI/NSUB
#define ST 17          // padded stride: (17c+d)%32 bijective over c => conflict-free

__device__ __forceinline__ float rcp_fast(float v) { return __builtin_amdgcn_rcpf(v); }

__global__ __launch_bounds__(NTHREADS)
void caps_em_kernel(const float* __restrict__ x, const float* __restrict__ Wg,
                    const float* __restrict__ beta_v, const float* __restrict__ beta_a,
                    float* __restrict__ out)
{
    __shared__ float MpL[KKI * 16];   // patch poses
    __shared__ float apL[KKI];        // patch activations
    __shared__ float T1L[NC * ST];    // sum_i Rw*v      (per iteration)
    __shared__ float S1L[NC * ST];    // sum_i v         (iteration-invariant)
    __shared__ float S2L[NC * ST];    // sum_i v^2       (iteration-invariant)
    __shared__ float ML[NC * ST];     // M
    __shared__ float I2L[NC * ST];    // 1/(2*var)
    __shared__ float RsumL[NC];
    __shared__ float constL[NC];      // log(a_j+eps) - sum_d log(stdv+eps)
    __shared__ float slogL[NC];       // sum_d log(stdv+eps)
    __shared__ float costL[NC];
    __shared__ float aoutL[NC];       // sigmoid(a_j)

    const int t = threadIdx.x;
    const int bid = blockIdx.x;           // b*144 + ho*12 + wo
    const int b = bid / 144;
    const int rem = bid - b * 144;
    const int ho = rem / 12;
    const int wo = rem - ho * 12;

    const int c = t & 31;
    const int isub = t >> 5;              // 0..31
    const int iBase = isub * IPT;

    // ---- stage patch tile: Mp[i][0..15], ap[i], i = p*32+cin, p = di*3+dj ----
    for (int idx = t; idx < KKI * 17; idx += NTHREADS) {
        int i = idx / 17;
        int e = idx - i * 17;
        int p = i >> 5, cin = i & 31;
        int di = p / 3, dj = p - di * 3;
        float vx = x[(((b * 14 + (ho + di)) * 14 + (wo + dj)) * 32 + cin) * 17 + e];
        if (e < 16) MpL[i * 16 + e] = vx; else apL[i] = vx;
    }
    for (int idx = t; idx < NC * ST; idx += NTHREADS) { T1L[idx] = 0.f; S1L[idx] = 0.f; S2L[idx] = 0.f; }
    if (t < NC) RsumL[t] = 0.f;
    __syncthreads();

    // stats phase A: 512 threads, one per (capsule c, dim d). Parallel
    // sqrt/log; 4-shuffle reduce over d (d occupies low 4 lane bits).
    auto statsA = [&]() {
        if (t < 512) {
            const int cc = t >> 4, d = t & 15;
            float rsum = RsumL[cc];
            float inv_rsum = rcp_fast(rsum);
            float m = T1L[cc * ST + d] * inv_rsum;
            // unweighted: var = sum_i (v - m)^2 = S2 - 2m S1 + KKI m^2
            float var = S2L[cc * ST + d] - 2.f * m * S1L[cc * ST + d] + 288.f * m * m;
            var = fmaxf(var, 0.f);
            float stdv = sqrtf(var);
            float lg = logf(stdv + EPSF);
            ML[cc * ST + d] = m;
            I2L[cc * ST + d] = 0.5f * rcp_fast(var);
            float sl = lg;
            sl += __shfl_xor(sl, 1); sl += __shfl_xor(sl, 2);
            sl += __shfl_xor(sl, 4); sl += __shfl_xor(sl, 8);
            if (d == 0) {
                slogL[cc] = sl;
                costL[cc] = rsum * (16.f * beta_v[cc] + sl);
            }
        }
    };
    // stats phase B: cross-capsule mean/std + activation, 32 threads.
    auto statsB = [&](float inv_temp) {
        if (t < 32) {
            float cost = costL[t];
            float csum = cost;
            csum += __shfl_xor(csum, 16); csum += __shfl_xor(csum, 8);
            csum += __shfl_xor(csum, 4);  csum += __shfl_xor(csum, 2);
            csum += __shfl_xor(csum, 1);
            float c_mean = csum * 0.03125f;
            float diff = cost - c_mean;
            float dsq = diff * diff;
            dsq += __shfl_xor(dsq, 16); dsq += __shfl_xor(dsq, 8);
            dsq += __shfl_xor(dsq, 4);  dsq += __shfl_xor(dsq, 2);
            dsq += __shfl_xor(dsq, 1);
            float c_stdv = sqrtf(dsq * 0.03125f);
            float a_cost = beta_a[t] + (c_mean - cost) * rcp_fast(c_stdv + EPSF);
            float a_j = 1.f / (1.f + expf(-inv_temp * a_cost));
            constL[t] = logf(a_j + EPSF) - slogL[t];
            aoutL[t] = 1.f / (1.f + expf(-a_j));
        }
    };

    // ---- pass 0: R uniform 1/32 -> Rw = ap/32; also build S1,S2 ----
    {
        float t1[16], s1[16], s2[16];
        #pragma unroll
        for (int d = 0; d < 16; ++d) { t1[d] = 0.f; s1[d] = 0.f; s2[d] = 0.f; }
        float rsum = 0.f;
        #pragma unroll
        for (int j = 0; j < IPT; ++j) {
            const int i = iBase + j;
            float wa[16], ma[16];
            const float4* w4 = (const float4*)(Wg + ((size_t)(i * NC + c) << 4));
            ((float4*)wa)[0] = w4[0]; ((float4*)wa)[1] = w4[1];
            ((float4*)wa)[2] = w4[2]; ((float4*)wa)[3] = w4[3];
            const float4* mp4 = (const float4*)(MpL + i * 16);
            ((float4*)ma)[0] = mp4[0]; ((float4*)ma)[1] = mp4[1];
            ((float4*)ma)[2] = mp4[2]; ((float4*)ma)[3] = mp4[3];
            float a_i = apL[i];
            float rw = a_i * 0.03125f;
            rsum += rw;
            #pragma unroll
            for (int p = 0; p < 4; ++p)
                #pragma unroll
                for (int r = 0; r < 4; ++r) {
                    float acc = ma[p * 4 + 0] * wa[0 * 4 + r];
                    acc = fmaf(ma[p * 4 + 1], wa[1 * 4 + r], acc);
                    acc = fmaf(ma[p * 4 + 2], wa[2 * 4 + r], acc);
                    acc = fmaf(ma[p * 4 + 3], wa[3 * 4 + r], acc);
                    const int d = p * 4 + r;
                    t1[d] = fmaf(rw, acc, t1[d]);
                    s1[d] += acc;
                    s2[d] = fmaf(acc, acc, s2[d]);
                }
        }
        rsum += __shfl_xor(rsum, 32);
        #pragma unroll
        for (int d = 0; d < 16; ++d) {
            t1[d] += __shfl_xor(t1[d], 32);
            s1[d] += __shfl_xor(s1[d], 32);
            s2[d] += __shfl_xor(s2[d], 32);
        }
        if ((t & 32) == 0) {
            atomicAdd(&RsumL[c], rsum);
            #pragma unroll
            for (int d = 0; d < 16; ++d) {
                atomicAdd(&T1L[c * ST + d], t1[d]);
                atomicAdd(&S1L[c * ST + d], s1[d]);
                atomicAdd(&S2L[c * ST + d], s2[d]);
            }
        }
        __syncthreads();
        statsA();
        __syncthreads();
        statsB(1.0f);   // it = 0
        __syncthreads();
    }

    // ---- passes 1,2: fused E-step (softmax over c, in-register) + M-step ----
    for (int it = 1; it < 3; ++it) {
        float Mreg[16], i2[16];
        #pragma unroll
        for (int d = 0; d < 16; ++d) { Mreg[d] = ML[c * ST + d]; i2[d] = I2L[c * ST + d]; }
        float Kc = constL[c];
        for (int idx = t; idx < NC * ST; idx += NTHREADS) T1L[idx] = 0.f;
        if (t < NC) RsumL[t] = 0.f;
        __syncthreads();

        float t1[16];
        #pragma unroll
        for (int d = 0; d < 16; ++d) t1[d] = 0.f;
        float rsum = 0.f;
        #pragma unroll
        for (int j = 0; j < IPT; ++j) {
            const int i = iBase + j;
            float wa[16], ma[16];
            const float4* w4 = (const float4*)(Wg + ((size_t)(i * NC + c) << 4));
            ((float4*)wa)[0] = w4[0]; ((float4*)wa)[1] = w4[1];
            ((float4*)wa)[2] = w4[2]; ((float4*)wa)[3] = w4[3];
            const float4* mp4 = (const float4*)(MpL + i * 16);
            ((float4*)ma)[0] = mp4[0]; ((float4*)ma)[1] = mp4[1];
            ((float4*)ma)[2] = mp4[2]; ((float4*)ma)[3] = mp4[3];
            float a_i = apL[i];
            float v[16];
            #pragma unroll
            for (int p = 0; p < 4; ++p)
                #pragma unroll
                for (int r = 0; r < 4; ++r) {
                    float acc = ma[p * 4 + 0] * wa[0 * 4 + r];
                    acc = fmaf(ma[p * 4 + 1], wa[1 * 4 + r], acc);
                    acc = fmaf(ma[p * 4 + 2], wa[2 * 4 + r], acc);
                    acc = fmaf(ma[p * 4 + 3], wa[3 * 4 + r], acc);
                    v[p * 4 + r] = acc;
                }
            float lp = Kc;
            #pragma unroll
            for (int d = 0; d < 16; ++d) {
                float df = v[d] - Mreg[d];
                lp = fmaf(-df * df, i2[d], lp);
            }
            // softmax over the 32 caps held by this half-wave
            float mx = lp;
            mx = fmaxf(mx, __shfl_xor(mx, 16)); mx = fmaxf(mx, __shfl_xor(mx, 8));
            mx = fmaxf(mx, __shfl_xor(mx, 4));  mx = fmaxf(mx, __shfl_xor(mx, 2));
            mx = fmaxf(mx, __shfl_xor(mx, 1));
            float ex = expf(lp - mx);
            float s = ex;
            s += __shfl_xor(s, 16); s += __shfl_xor(s, 8);
            s += __shfl_xor(s, 4);  s += __shfl_xor(s, 2);
            s += __shfl_xor(s, 1);
            float r = ex * rcp_fast(s);
            float rw = r * a_i;
            rsum += rw;
            #pragma unroll
            for (int d = 0; d < 16; ++d) t1[d] = fmaf(rw, v[d], t1[d]);
        }
        rsum += __shfl_xor(rsum, 32);
        #pragma unroll
        for (int d = 0; d < 16; ++d) t1[d] += __shfl_xor(t1[d], 32);
        if ((t & 32) == 0) {
            atomicAdd(&RsumL[c], rsum);
            #pragma unroll
            for (int d = 0; d < 16; ++d) atomicAdd(&T1L[c * ST + d], t1[d]);
        }
        __syncthreads();
        statsA();
        __syncthreads();
        statsB(1.0f + (float)it);   // inv_temp = 1 + it
        __syncthreads();
    }

    // ---- epilogue: out[b,ho,wo,c,0:16]=M, out[...,16]=sigmoid(a_j) ----
    // output stride per capsule is 17 == ST, so ML indexes line up directly.
    for (int idx = t; idx < NC * 17; idx += NTHREADS) {
        int cc = idx / 17;
        int e = idx - cc * 17;
        float val = (e < 16) ? ML[idx] : aoutL[cc];
        out[(size_t)bid * (NC * 17) + idx] = val;
    }
}

extern "C" void kernel_launch(void* const* d_in, const int* in_sizes, int n_in,
                              void* d_out, int out_size, void* d_ws, size_t ws_size,
                              hipStream_t stream) {
    const float* x  = (const float*)d_in[0];
    const float* W  = (const float*)d_in[1];
    const float* bv = (const float*)d_in[2];
    const float* ba = (const float*)d_in[3];
    float* out = (float*)d_out;
    // grid = B*Ho*Wo = 2*12*12 = 288 positions, one block each
    caps_em_kernel<<<288, NTHREADS, 0, stream>>>(x, W, bv, ba, out);
}

// Round 3
// 232.736 us; speedup vs baseline: 1.4180x; 1.4180x over previous
//
#include <hip/hip_runtime.h>
#include <math.h>

// ConvolutionalCapsule with EM routing, fully fused: one block per output
// position (b,ho,wo). Votes V[i,c,d] (288x32x16 per position) are NEVER
// materialized: recomputed from LDS patch tile + L2-resident W each pass.
// Key algebraic facts:
//  - reference stdv uses Rsum (not Rw) => var = UNWEIGHTED sum_i (v-M)^2,
//    so S1=sum_i v, S2=sum_i v^2 are iteration-invariant (computed once).
//  - E-step softmax over 32 caps is shift-invariant; quad term in [0,8]
//    (df^2 <= var termwise => sum_d df^2/(2var) <= 8). Subtracting the
//    per-pass constant Kmax = max_c Kc bounds exp2 args in [-inf,0] with
//    denominator >= e^-8: NO per-i max reduction needed (saves a 5-deep
//    dependent shuffle chain per j-iteration).
//  - cost = rsum * (16*beta_v + sum_d log(stdv+eps)): one d-reduction only.
// Round-3 (vs round-1 PASSED/330us, round-2 FAILED):
//  - __launch_bounds__(1024,4): 16 waves = 4 waves/SIMD, VGPR cap 128.
//    (round-1 regression: bare (1024) => cap 64 => spills, FETCH 154MB.)
//  - j-loops NOT unrolled (bounds live ranges under the 128 cap).
//  - Kmax trick + exp2-space softmax (exact exp2f).
//  - stats parallelized: 512 threads (one per (c,d)) + 32-thread tail.
//  - ALL cross-lane ops are round-1-proven __shfl_xor; round-2's DPP /
//    permlane32_swap primitives removed pending isolated A/B.
// Thread map (round-1-proven): c = t&31, isub = t>>5 (0..31), i = isub*9+j.
// Half-wave shares i (broadcast LDS reads, contiguous 2KB W row reads).

#define EPSF 1e-7f
#define KKI 288
#define NC 32
#define NTHREADS 1024
#define IPT 9           // KKI / 32 half-waves
#define ST 17           // padded stride: (17c+d)%32 bijective over c
#define L2E 1.4426950408889634f

__device__ __forceinline__ float rcp_fast(float v) { return __builtin_amdgcn_rcpf(v); }

__global__ __launch_bounds__(NTHREADS, 4)
void caps_em_kernel(const float* __restrict__ x, const float* __restrict__ Wg,
                    const float* __restrict__ beta_v, const float* __restrict__ beta_a,
                    float* __restrict__ out)
{
    __shared__ float MpL[KKI * 16];   // patch poses
    __shared__ float apL[KKI];        // patch activations
    __shared__ float T1L[NC * ST];    // sum_i Rw*v      (per iteration)
    __shared__ float S1L[NC * ST];    // sum_i v         (iteration-invariant)
    __shared__ float S2L[NC * ST];    // sum_i v^2       (iteration-invariant)
    __shared__ float ML[NC * ST];     // M
    __shared__ float I2L[NC * ST];    // 0.5/var
    __shared__ float RsumL[NC];
    __shared__ float constL[NC];      // Kc = log(a_j+eps) - sum_d log(stdv+eps)
    __shared__ float slogL[NC];
    __shared__ float costL[NC];
    __shared__ float aoutL[NC];       // sigmoid(a_j)
    __shared__ float KmaxL;           // max_c Kc

    const int t = threadIdx.x;
    const int bid = blockIdx.x;           // b*144 + ho*12 + wo
    const int b = bid / 144;
    const int rem = bid - b * 144;
    const int ho = rem / 12;
    const int wo = rem - ho * 12;

    const int c = t & 31;
    const int isub = t >> 5;              // 0..31
    const int iBase = isub * IPT;

    // ---- stage patch tile: Mp[i][0..15], ap[i], i = p*32+cin, p = di*3+dj ----
    for (int idx = t; idx < KKI * 17; idx += NTHREADS) {
        int i = idx / 17;
        int e = idx - i * 17;
        int p = i >> 5, cin = i & 31;
        int di = p / 3, dj = p - di * 3;
        float vx = x[(((b * 14 + (ho + di)) * 14 + (wo + dj)) * 32 + cin) * 17 + e];
        if (e < 16) MpL[i * 16 + e] = vx; else apL[i] = vx;
    }
    if (t < NC * ST) { T1L[t] = 0.f; S1L[t] = 0.f; S2L[t] = 0.f; }
    if (t < NC) RsumL[t] = 0.f;
    __syncthreads();

    // stats A: one thread per (capsule cc, dim d); d = lane bits 0-3 so the
    // slog reduction is a 4-step shfl_xor row sum.
    auto statsA = [&]() {
        if (t < 512) {
            const int cc = t >> 4, d = t & 15;
            float rsum = RsumL[cc];
            float m = T1L[cc * ST + d] * rcp_fast(rsum);
            float var = S2L[cc * ST + d] - 2.f * m * S1L[cc * ST + d] + 288.f * m * m;
            var = fmaxf(var, 0.f);
            float lg = logf(sqrtf(var) + EPSF);
            ML[cc * ST + d] = m;
            I2L[cc * ST + d] = 0.5f * rcp_fast(var);
            float sl = lg;
            sl += __shfl_xor(sl, 1); sl += __shfl_xor(sl, 2);
            sl += __shfl_xor(sl, 4); sl += __shfl_xor(sl, 8);
            if (d == 0) {
                slogL[cc] = sl;
                costL[cc] = rsum * (16.f * beta_v[cc] + sl);
            }
        }
    };
    // stats B: cross-capsule mean/std + activation + Kmax (32 threads).
    auto statsB = [&](float inv_temp) {
        if (t < 32) {
            float cost = costL[t];
            float csum = cost;
            csum += __shfl_xor(csum, 16); csum += __shfl_xor(csum, 8);
            csum += __shfl_xor(csum, 4);  csum += __shfl_xor(csum, 2);
            csum += __shfl_xor(csum, 1);
            float c_mean = csum * 0.03125f;
            float diff = cost - c_mean;
            float dsq = diff * diff;
            dsq += __shfl_xor(dsq, 16); dsq += __shfl_xor(dsq, 8);
            dsq += __shfl_xor(dsq, 4);  dsq += __shfl_xor(dsq, 2);
            dsq += __shfl_xor(dsq, 1);
            float c_stdv = sqrtf(dsq * 0.03125f);
            float a_cost = beta_a[t] + (c_mean - cost) * rcp_fast(c_stdv + EPSF);
            float a_j = 1.f / (1.f + expf(-inv_temp * a_cost));
            float kc = logf(a_j + EPSF) - slogL[t];
            constL[t] = kc;
            aoutL[t] = 1.f / (1.f + expf(-a_j));
            float km = kc;
            km = fmaxf(km, __shfl_xor(km, 16)); km = fmaxf(km, __shfl_xor(km, 8));
            km = fmaxf(km, __shfl_xor(km, 4));  km = fmaxf(km, __shfl_xor(km, 2));
            km = fmaxf(km, __shfl_xor(km, 1));
            if (t == 0) KmaxL = km;
        }
    };

    // ---- pass 0: R uniform 1/32 -> Rw = ap/32; also build S1,S2 ----
    {
        float t1[16], s1[16], s2[16];
        #pragma unroll
        for (int d = 0; d < 16; ++d) { t1[d] = 0.f; s1[d] = 0.f; s2[d] = 0.f; }
        float rsum = 0.f;
        for (int j = 0; j < IPT; ++j) {
            const int i = iBase + j;
            float wa[16], ma[16];
            const float4* w4 = (const float4*)(Wg + ((size_t)((i << 5) + c) << 4));
            ((float4*)wa)[0] = w4[0]; ((float4*)wa)[1] = w4[1];
            ((float4*)wa)[2] = w4[2]; ((float4*)wa)[3] = w4[3];
            const float4* mp4 = (const float4*)(MpL + (i << 4));
            ((float4*)ma)[0] = mp4[0]; ((float4*)ma)[1] = mp4[1];
            ((float4*)ma)[2] = mp4[2]; ((float4*)ma)[3] = mp4[3];
            float rw = apL[i] * 0.03125f;
            rsum += rw;
            #pragma unroll
            for (int p = 0; p < 4; ++p)
                #pragma unroll
                for (int r = 0; r < 4; ++r) {
                    float acc = ma[p * 4 + 0] * wa[0 * 4 + r];
                    acc = fmaf(ma[p * 4 + 1], wa[1 * 4 + r], acc);
                    acc = fmaf(ma[p * 4 + 2], wa[2 * 4 + r], acc);
                    acc = fmaf(ma[p * 4 + 3], wa[3 * 4 + r], acc);
                    const int d = p * 4 + r;
                    t1[d] = fmaf(rw, acc, t1[d]);
                    s1[d] += acc;
                    s2[d] = fmaf(acc, acc, s2[d]);
                }
        }
        // combine partner half-waves (lane^32 shares c), then 32 lanes atomic
        rsum += __shfl_xor(rsum, 32);
        #pragma unroll
        for (int d = 0; d < 16; ++d) {
            t1[d] += __shfl_xor(t1[d], 32);
            s1[d] += __shfl_xor(s1[d], 32);
            s2[d] += __shfl_xor(s2[d], 32);
        }
        if ((t & 32) == 0) {
            atomicAdd(&RsumL[c], rsum);
            #pragma unroll
            for (int d = 0; d < 16; ++d) {
                atomicAdd(&T1L[c * ST + d], t1[d]);
                atomicAdd(&S1L[c * ST + d], s1[d]);
                atomicAdd(&S2L[c * ST + d], s2[d]);
            }
        }
        __syncthreads();
        statsA();
        __syncthreads();
        statsB(1.0f);   // it = 0
        __syncthreads();
    }

    // ---- passes 1,2: fused E-step (softmax over c, in-register) + M-step ----
    for (int it = 1; it < 3; ++it) {
        float Mreg[16], i2[16];
        #pragma unroll
        for (int d = 0; d < 16; ++d) {
            Mreg[d] = ML[c * ST + d];
            i2[d]   = I2L[c * ST + d] * L2E;   // log2-space quadratic
        }
        float Kc2 = (constL[c] - KmaxL) * L2E; // exp2 arg <= 0 always
        __syncthreads();                       // all reads done before re-zero
        if (t < NC * ST) T1L[t] = 0.f;
        if (t < NC) RsumL[t] = 0.f;
        __syncthreads();

        float t1[16];
        #pragma unroll
        for (int d = 0; d < 16; ++d) t1[d] = 0.f;
        float rsum = 0.f;
        for (int j = 0; j < IPT; ++j) {
            const int i = iBase + j;
            float wa[16], ma[16];
            const float4* w4 = (const float4*)(Wg + ((size_t)((i << 5) + c) << 4));
            ((float4*)wa)[0] = w4[0]; ((float4*)wa)[1] = w4[1];
            ((float4*)wa)[2] = w4[2]; ((float4*)wa)[3] = w4[3];
            const float4* mp4 = (const float4*)(MpL + (i << 4));
            ((float4*)ma)[0] = mp4[0]; ((float4*)ma)[1] = mp4[1];
            ((float4*)ma)[2] = mp4[2]; ((float4*)ma)[3] = mp4[3];
            float a_i = apL[i];
            float v[16];
            #pragma unroll
            for (int p = 0; p < 4; ++p)
                #pragma unroll
                for (int r = 0; r < 4; ++r) {
                    float acc = ma[p * 4 + 0] * wa[0 * 4 + r];
                    acc = fmaf(ma[p * 4 + 1], wa[1 * 4 + r], acc);
                    acc = fmaf(ma[p * 4 + 2], wa[2 * 4 + r], acc);
                    acc = fmaf(ma[p * 4 + 3], wa[3 * 4 + r], acc);
                    v[p * 4 + r] = acc;
                }
            float lp2 = Kc2;
            #pragma unroll
            for (int d = 0; d < 16; ++d) {
                float df = v[d] - Mreg[d];
                lp2 = fmaf(-df * df, i2[d], lp2);
            }
            float ex = exp2f(lp2);             // <= 1; denom >= e^-8: safe
            // softmax denominator: sum over the 32 caps of this half-wave
            float ssum = ex;
            ssum += __shfl_xor(ssum, 16); ssum += __shfl_xor(ssum, 8);
            ssum += __shfl_xor(ssum, 4);  ssum += __shfl_xor(ssum, 2);
            ssum += __shfl_xor(ssum, 1);
            float rw = ex * rcp_fast(ssum) * a_i;
            rsum += rw;
            #pragma unroll
            for (int d = 0; d < 16; ++d) t1[d] = fmaf(rw, v[d], t1[d]);
        }
        rsum += __shfl_xor(rsum, 32);
        #pragma unroll
        for (int d = 0; d < 16; ++d) t1[d] += __shfl_xor(t1[d], 32);
        if ((t & 32) == 0) {
            atomicAdd(&RsumL[c], rsum);
            #pragma unroll
            for (int d = 0; d < 16; ++d) atomicAdd(&T1L[c * ST + d], t1[d]);
        }
        __syncthreads();
        statsA();
        __syncthreads();
        statsB(1.0f + (float)it);   // inv_temp = 1 + it
        __syncthreads();
    }

    // ---- epilogue: out[b,ho,wo,c,0:16]=M, out[...,16]=sigmoid(a_j) ----
    // output stride per capsule is 17 == ST, so ML indexes line up directly.
    if (t < NC * 17) {
        int cc = t / 17;
        int e = t - cc * 17;
        float val = (e < 16) ? ML[t] : aoutL[cc];
        out[(size_t)bid * (NC * 17) + t] = val;
    }
}

extern "C" void kernel_launch(void* const* d_in, const int* in_sizes, int n_in,
                              void* d_out, int out_size, void* d_ws, size_t ws_size,
                              hipStream_t stream) {
    const float* x  = (const float*)d_in[0];
    const float* W  = (const float*)d_in[1];
    const float* bv = (const float*)d_in[2];
    const float* ba = (const float*)d_in[3];
    float* out = (float*)d_out;
    // grid = B*Ho*Wo = 2*12*12 = 288 positions, one block each
    caps_em_kernel<<<288, NTHREADS, 0, stream>>>(x, W, bv, ba, out);
}

// Round 4
// 230.078 us; speedup vs baseline: 1.4344x; 1.0116x over previous
//
#include <hip/hip_runtime.h>
#include <math.h>

// ConvolutionalCapsule with EM routing, fully fused: one block per output
// position (b,ho,wo). Votes V[i,c,d] (288x32x16 per position) are NEVER
// materialized: recomputed from LDS patch tile + L2-resident W each pass.
// Key algebraic facts:
//  - reference stdv uses Rsum (not Rw) => var = UNWEIGHTED sum_i (v-M)^2,
//    so S1=sum_i v, S2=sum_i v^2 are iteration-invariant (computed once).
//  - E-step softmax over 32 caps is shift-invariant; quad term in [0,8]
//    (df^2 <= var termwise => sum_d df^2/(2var) <= 8). Subtracting the
//    per-pass constant Kmax = max_c Kc bounds exp2 args in [-inf,0] with
//    denominator >= e^-8: NO per-i max reduction needed (saves a 5-deep
//    dependent shuffle chain per j-iteration).
//  - cost = rsum * (16*beta_v + sum_d log(stdv+eps)): one d-reduction only.
// Round-4 (vs round-3 PASSED/183us-rocprof):
//  - ONLY change: occupancy attribute. Round 1 bare (1024) AND round 3
//    (1024,4) both produced VGPR_Count=64 (compiler targeted 2 blocks/CU,
//    unusable: grid is 288 blocks / 256 CUs) => ~45 regs spilled/thread,
//    WRITE_SIZE 14.5MB vs 0.6MB real output. Explicit
//    amdgpu_waves_per_eu(4,4) pins exactly 4 waves/EU = 1 block/CU =>
//    VGPR budget 512/4 = 128 >= ~110 demand => no spill.
// Thread map (round-1-proven): c = t&31, isub = t>>5 (0..31), i = isub*9+j.
// Half-wave shares i (broadcast LDS reads, contiguous 2KB W row reads).

#define EPSF 1e-7f
#define KKI 288
#define NC 32
#define NTHREADS 1024
#define IPT 9           // KKI / 32 half-waves
#define ST 17           // padded stride: (17c+d)%32 bijective over c
#define L2E 1.4426950408889634f

__device__ __forceinline__ float rcp_fast(float v) { return __builtin_amdgcn_rcpf(v); }

__global__
__attribute__((amdgpu_flat_work_group_size(NTHREADS, NTHREADS)))
__attribute__((amdgpu_waves_per_eu(4, 4)))
void caps_em_kernel(const float* __restrict__ x, const float* __restrict__ Wg,
                    const float* __restrict__ beta_v, const float* __restrict__ beta_a,
                    float* __restrict__ out)
{
    __shared__ float MpL[KKI * 16];   // patch poses
    __shared__ float apL[KKI];        // patch activations
    __shared__ float T1L[NC * ST];    // sum_i Rw*v      (per iteration)
    __shared__ float S1L[NC * ST];    // sum_i v         (iteration-invariant)
    __shared__ float S2L[NC * ST];    // sum_i v^2       (iteration-invariant)
    __shared__ float ML[NC * ST];     // M
    __shared__ float I2L[NC * ST];    // 0.5/var
    __shared__ float RsumL[NC];
    __shared__ float constL[NC];      // Kc = log(a_j+eps) - sum_d log(stdv+eps)
    __shared__ float slogL[NC];
    __shared__ float costL[NC];
    __shared__ float aoutL[NC];       // sigmoid(a_j)
    __shared__ float KmaxL;           // max_c Kc

    const int t = threadIdx.x;
    const int bid = blockIdx.x;           // b*144 + ho*12 + wo
    const int b = bid / 144;
    const int rem = bid - b * 144;
    const int ho = rem / 12;
    const int wo = rem - ho * 12;

    const int c = t & 31;
    const int isub = t >> 5;              // 0..31
    const int iBase = isub * IPT;

    // ---- stage patch tile: Mp[i][0..15], ap[i], i = p*32+cin, p = di*3+dj ----
    for (int idx = t; idx < KKI * 17; idx += NTHREADS) {
        int i = idx / 17;
        int e = idx - i * 17;
        int p = i >> 5, cin = i & 31;
        int di = p / 3, dj = p - di * 3;
        float vx = x[(((b * 14 + (ho + di)) * 14 + (wo + dj)) * 32 + cin) * 17 + e];
        if (e < 16) MpL[i * 16 + e] = vx; else apL[i] = vx;
    }
    if (t < NC * ST) { T1L[t] = 0.f; S1L[t] = 0.f; S2L[t] = 0.f; }
    if (t < NC) RsumL[t] = 0.f;
    __syncthreads();

    // stats A: one thread per (capsule cc, dim d); d = lane bits 0-3 so the
    // slog reduction is a 4-step shfl_xor row sum.
    auto statsA = [&]() {
        if (t < 512) {
            const int cc = t >> 4, d = t & 15;
            float rsum = RsumL[cc];
            float m = T1L[cc * ST + d] * rcp_fast(rsum);
            float var = S2L[cc * ST + d] - 2.f * m * S1L[cc * ST + d] + 288.f * m * m;
            var = fmaxf(var, 0.f);
            float lg = logf(sqrtf(var) + EPSF);
            ML[cc * ST + d] = m;
            I2L[cc * ST + d] = 0.5f * rcp_fast(var);
            float sl = lg;
            sl += __shfl_xor(sl, 1); sl += __shfl_xor(sl, 2);
            sl += __shfl_xor(sl, 4); sl += __shfl_xor(sl, 8);
            if (d == 0) {
                slogL[cc] = sl;
                costL[cc] = rsum * (16.f * beta_v[cc] + sl);
            }
        }
    };
    // stats B: cross-capsule mean/std + activation + Kmax (32 threads).
    auto statsB = [&](float inv_temp) {
        if (t < 32) {
            float cost = costL[t];
            float csum = cost;
            csum += __shfl_xor(csum, 16); csum += __shfl_xor(csum, 8);
            csum += __shfl_xor(csum, 4);  csum += __shfl_xor(csum, 2);
            csum += __shfl_xor(csum, 1);
            float c_mean = csum * 0.03125f;
            float diff = cost - c_mean;
            float dsq = diff * diff;
            dsq += __shfl_xor(dsq, 16); dsq += __shfl_xor(dsq, 8);
            dsq += __shfl_xor(dsq, 4);  dsq += __shfl_xor(dsq, 2);
            dsq += __shfl_xor(dsq, 1);
            float c_stdv = sqrtf(dsq * 0.03125f);
            float a_cost = beta_a[t] + (c_mean - cost) * rcp_fast(c_stdv + EPSF);
            float a_j = 1.f / (1.f + expf(-inv_temp * a_cost));
            float kc = logf(a_j + EPSF) - slogL[t];
            constL[t] = kc;
            aoutL[t] = 1.f / (1.f + expf(-a_j));
            float km = kc;
            km = fmaxf(km, __shfl_xor(km, 16)); km = fmaxf(km, __shfl_xor(km, 8));
            km = fmaxf(km, __shfl_xor(km, 4));  km = fmaxf(km, __shfl_xor(km, 2));
            km = fmaxf(km, __shfl_xor(km, 1));
            if (t == 0) KmaxL = km;
        }
    };

    // ---- pass 0: R uniform 1/32 -> Rw = ap/32; also build S1,S2 ----
    {
        float t1[16], s1[16], s2[16];
        #pragma unroll
        for (int d = 0; d < 16; ++d) { t1[d] = 0.f; s1[d] = 0.f; s2[d] = 0.f; }
        float rsum = 0.f;
        for (int j = 0; j < IPT; ++j) {
            const int i = iBase + j;
            float wa[16], ma[16];
            const float4* w4 = (const float4*)(Wg + ((size_t)((i << 5) + c) << 4));
            ((float4*)wa)[0] = w4[0]; ((float4*)wa)[1] = w4[1];
            ((float4*)wa)[2] = w4[2]; ((float4*)wa)[3] = w4[3];
            const float4* mp4 = (const float4*)(MpL + (i << 4));
            ((float4*)ma)[0] = mp4[0]; ((float4*)ma)[1] = mp4[1];
            ((float4*)ma)[2] = mp4[2]; ((float4*)ma)[3] = mp4[3];
            float rw = apL[i] * 0.03125f;
            rsum += rw;
            #pragma unroll
            for (int p = 0; p < 4; ++p)
                #pragma unroll
                for (int r = 0; r < 4; ++r) {
                    float acc = ma[p * 4 + 0] * wa[0 * 4 + r];
                    acc = fmaf(ma[p * 4 + 1], wa[1 * 4 + r], acc);
                    acc = fmaf(ma[p * 4 + 2], wa[2 * 4 + r], acc);
                    acc = fmaf(ma[p * 4 + 3], wa[3 * 4 + r], acc);
                    const int d = p * 4 + r;
                    t1[d] = fmaf(rw, acc, t1[d]);
                    s1[d] += acc;
                    s2[d] = fmaf(acc, acc, s2[d]);
                }
        }
        // combine partner half-waves (lane^32 shares c), then 32 lanes atomic
        rsum += __shfl_xor(rsum, 32);
        #pragma unroll
        for (int d = 0; d < 16; ++d) {
            t1[d] += __shfl_xor(t1[d], 32);
            s1[d] += __shfl_xor(s1[d], 32);
            s2[d] += __shfl_xor(s2[d], 32);
        }
        if ((t & 32) == 0) {
            atomicAdd(&RsumL[c], rsum);
            #pragma unroll
            for (int d = 0; d < 16; ++d) {
                atomicAdd(&T1L[c * ST + d], t1[d]);
                atomicAdd(&S1L[c * ST + d], s1[d]);
                atomicAdd(&S2L[c * ST + d], s2[d]);
            }
        }
        __syncthreads();
        statsA();
        __syncthreads();
        statsB(1.0f);   // it = 0
        __syncthreads();
    }

    // ---- passes 1,2: fused E-step (softmax over c, in-register) + M-step ----
    for (int it = 1; it < 3; ++it) {
        float Mreg[16], i2[16];
        #pragma unroll
        for (int d = 0; d < 16; ++d) {
            Mreg[d] = ML[c * ST + d];
            i2[d]   = I2L[c * ST + d] * L2E;   // log2-space quadratic
        }
        float Kc2 = (constL[c] - KmaxL) * L2E; // exp2 arg <= 0 always
        __syncthreads();                       // all reads done before re-zero
        if (t < NC * ST) T1L[t] = 0.f;
        if (t < NC) RsumL[t] = 0.f;
        __syncthreads();

        float t1[16];
        #pragma unroll
        for (int d = 0; d < 16; ++d) t1[d] = 0.f;
        float rsum = 0.f;
        for (int j = 0; j < IPT; ++j) {
            const int i = iBase + j;
            float wa[16], ma[16];
            const float4* w4 = (const float4*)(Wg + ((size_t)((i << 5) + c) << 4));
            ((float4*)wa)[0] = w4[0]; ((float4*)wa)[1] = w4[1];
            ((float4*)wa)[2] = w4[2]; ((float4*)wa)[3] = w4[3];
            const float4* mp4 = (const float4*)(MpL + (i << 4));
            ((float4*)ma)[0] = mp4[0]; ((float4*)ma)[1] = mp4[1];
            ((float4*)ma)[2] = mp4[2]; ((float4*)ma)[3] = mp4[3];
            float a_i = apL[i];
            float v[16];
            #pragma unroll
            for (int p = 0; p < 4; ++p)
                #pragma unroll
                for (int r = 0; r < 4; ++r) {
                    float acc = ma[p * 4 + 0] * wa[0 * 4 + r];
                    acc = fmaf(ma[p * 4 + 1], wa[1 * 4 + r], acc);
                    acc = fmaf(ma[p * 4 + 2], wa[2 * 4 + r], acc);
                    acc = fmaf(ma[p * 4 + 3], wa[3 * 4 + r], acc);
                    v[p * 4 + r] = acc;
                }
            float lp2 = Kc2;
            #pragma unroll
            for (int d = 0; d < 16; ++d) {
                float df = v[d] - Mreg[d];
                lp2 = fmaf(-df * df, i2[d], lp2);
            }
            float ex = exp2f(lp2);             // <= 1; denom >= e^-8: safe
            // softmax denominator: sum over the 32 caps of this half-wave
            float ssum = ex;
            ssum += __shfl_xor(ssum, 16); ssum += __shfl_xor(ssum, 8);
            ssum += __shfl_xor(ssum, 4);  ssum += __shfl_xor(ssum, 2);
            ssum += __shfl_xor(ssum, 1);
            float rw = ex * rcp_fast(ssum) * a_i;
            rsum += rw;
            #pragma unroll
            for (int d = 0; d < 16; ++d) t1[d] = fmaf(rw, v[d], t1[d]);
        }
        rsum += __shfl_xor(rsum, 32);
        #pragma unroll
        for (int d = 0; d < 16; ++d) t1[d] += __shfl_xor(t1[d], 32);
        if ((t & 32) == 0) {
            atomicAdd(&RsumL[c], rsum);
            #pragma unroll
            for (int d = 0; d < 16; ++d) atomicAdd(&T1L[c * ST + d], t1[d]);
        }
        __syncthreads();
        statsA();
        __syncthreads();
        statsB(1.0f + (float)it);   // inv_temp = 1 + it
        __syncthreads();
    }

    // ---- epilogue: out[b,ho,wo,c,0:16]=M, out[...,16]=sigmoid(a_j) ----
    // output stride per capsule is 17 == ST, so ML indexes line up directly.
    if (t < NC * 17) {
        int cc = t / 17;
        int e = t - cc * 17;
        float val = (e < 16) ? ML[t] : aoutL[cc];
        out[(size_t)bid * (NC * 17) + t] = val;
    }
}

extern "C" void kernel_launch(void* const* d_in, const int* in_sizes, int n_in,
                              void* d_out, int out_size, void* d_ws, size_t ws_size,
                              hipStream_t stream) {
    const float* x  = (const float*)d_in[0];
    const float* W  = (const float*)d_in[1];
    const float* bv = (const float*)d_in[2];
    const float* ba = (const float*)d_in[3];
    float* out = (float*)d_out;
    // grid = B*Ho*Wo = 2*12*12 = 288 positions, one block each
    caps_em_kernel<<<288, NTHREADS, 0, stream>>>(x, W, bv, ba, out);
}

// Round 5
// 227.905 us; speedup vs baseline: 1.4481x; 1.0095x over previous
//
#include <hip/hip_runtime.h>
#include <math.h>

// ConvolutionalCapsule with EM routing, fully fused: one block per output
// position (b,ho,wo). Votes V[i,c,d] (288x32x16 per position) are NEVER
// materialized: recomputed from LDS patch tile + L2-resident W each pass.
// Key algebraic facts:
//  - reference stdv uses Rsum (not Rw) => var = UNWEIGHTED sum_i (v-M)^2,
//    so S1=sum_i v, S2=sum_i v^2 are iteration-invariant (computed once).
//  - E-step softmax over 32 caps is shift-invariant; quad term in [0,8]
//    => subtracting per-pass Kmax = max_c Kc bounds exp2 args <= 0 with
//    denominator >= e^-8: NO per-i max reduction needed.
//  - cost = rsum * (16*beta_v + sum_d log(stdv+eps)): one d-reduction only.
// Round-5 (vs round-4 PASSED/180us-rocprof, VGPR still 64 + spills):
//  - ONLY change: LDS occupancy pad. R4 evidence: waves_per_eu(4,4) reached
//    codegen (SGPR 48->112) but VGPR stayed 64 (spills: WRITE 6.8MB vs
//    0.63MB real). Theory: LDS-implied occupancy (31232B => >=2 blocks/CU
//    => 8 waves/EU => 64-VGPR budget) overrides the requested 4 waves/EU.
//    Padding LDS to ~82.4KB (> half of 160KB pool) forces 1 block/CU =>
//    all mechanisms agree on 4 waves/EU => budget 128 >= ~90 demand =>
//    no spill. Grid is 288 blocks/256 CUs so a 2nd resident block was
//    nearly useless anyway. (>64KB static LDS on gfx950 is proven: the
//    128KiB 8-phase GEMM template compiles.)
// Thread map (round-1-proven): c = t&31, isub = t>>5 (0..31), i = isub*9+j.
// Half-wave shares i (broadcast LDS reads, contiguous 2KB W row reads).

#define EPSF 1e-7f
#define KKI 288
#define NC 32
#define NTHREADS 1024
#define IPT 9           // KKI / 32 half-waves
#define ST 17           // padded stride: (17c+d)%32 bijective over c
#define L2E 1.4426950408889634f
#define PAD_FLOATS 12800   // 51200B: total LDS ~82.4KB > 80KB => 1 block/CU

__device__ __forceinline__ float rcp_fast(float v) { return __builtin_amdgcn_rcpf(v); }

__global__
__attribute__((amdgpu_flat_work_group_size(NTHREADS, NTHREADS)))
__attribute__((amdgpu_waves_per_eu(4, 4)))
void caps_em_kernel(const float* __restrict__ x, const float* __restrict__ Wg,
                    const float* __restrict__ beta_v, const float* __restrict__ beta_a,
                    float* __restrict__ out)
{
    __shared__ float MpL[KKI * 16];   // patch poses
    __shared__ float apL[KKI];        // patch activations
    __shared__ float T1L[NC * ST];    // sum_i Rw*v      (per iteration)
    __shared__ float S1L[NC * ST];    // sum_i v         (iteration-invariant)
    __shared__ float S2L[NC * ST];    // sum_i v^2       (iteration-invariant)
    __shared__ float ML[NC * ST];     // M
    __shared__ float I2L[NC * ST];    // 0.5/var
    __shared__ float RsumL[NC];
    __shared__ float constL[NC];      // Kc = log(a_j+eps) - sum_d log(stdv+eps)
    __shared__ float slogL[NC];
    __shared__ float costL[NC];
    __shared__ float aoutL[NC];       // sigmoid(a_j)
    __shared__ float KmaxL;           // max_c Kc
    __shared__ float occPad[PAD_FLOATS];  // never read: LDS occupancy pad

    const int t = threadIdx.x;
    // volatile touch so occPad is allocated but costs one store from t0 only
    if (t == 0) *(volatile float*)occPad = 0.f;

    const int bid = blockIdx.x;           // b*144 + ho*12 + wo
    const int b = bid / 144;
    const int rem = bid - b * 144;
    const int ho = rem / 12;
    const int wo = rem - ho * 12;

    const int c = t & 31;
    const int isub = t >> 5;              // 0..31
    const int iBase = isub * IPT;

    // ---- stage patch tile: Mp[i][0..15], ap[i], i = p*32+cin, p = di*3+dj ----
    for (int idx = t; idx < KKI * 17; idx += NTHREADS) {
        int i = idx / 17;
        int e = idx - i * 17;
        int p = i >> 5, cin = i & 31;
        int di = p / 3, dj = p - di * 3;
        float vx = x[(((b * 14 + (ho + di)) * 14 + (wo + dj)) * 32 + cin) * 17 + e];
        if (e < 16) MpL[i * 16 + e] = vx; else apL[i] = vx;
    }
    if (t < NC * ST) { T1L[t] = 0.f; S1L[t] = 0.f; S2L[t] = 0.f; }
    if (t < NC) RsumL[t] = 0.f;
    __syncthreads();

    // stats A: one thread per (capsule cc, dim d); d = lane bits 0-3 so the
    // slog reduction is a 4-step shfl_xor row sum.
    auto statsA = [&]() {
        if (t < 512) {
            const int cc = t >> 4, d = t & 15;
            float rsum = RsumL[cc];
            float m = T1L[cc * ST + d] * rcp_fast(rsum);
            float var = S2L[cc * ST + d] - 2.f * m * S1L[cc * ST + d] + 288.f * m * m;
            var = fmaxf(var, 0.f);
            float lg = logf(sqrtf(var) + EPSF);
            ML[cc * ST + d] = m;
            I2L[cc * ST + d] = 0.5f * rcp_fast(var);
            float sl = lg;
            sl += __shfl_xor(sl, 1); sl += __shfl_xor(sl, 2);
            sl += __shfl_xor(sl, 4); sl += __shfl_xor(sl, 8);
            if (d == 0) {
                slogL[cc] = sl;
                costL[cc] = rsum * (16.f * beta_v[cc] + sl);
            }
        }
    };
    // stats B: cross-capsule mean/std + activation + Kmax (32 threads).
    auto statsB = [&](float inv_temp) {
        if (t < 32) {
            float cost = costL[t];
            float csum = cost;
            csum += __shfl_xor(csum, 16); csum += __shfl_xor(csum, 8);
            csum += __shfl_xor(csum, 4);  csum += __shfl_xor(csum, 2);
            csum += __shfl_xor(csum, 1);
            float c_mean = csum * 0.03125f;
            float diff = cost - c_mean;
            float dsq = diff * diff;
            dsq += __shfl_xor(dsq, 16); dsq += __shfl_xor(dsq, 8);
            dsq += __shfl_xor(dsq, 4);  dsq += __shfl_xor(dsq, 2);
            dsq += __shfl_xor(dsq, 1);
            float c_stdv = sqrtf(dsq * 0.03125f);
            float a_cost = beta_a[t] + (c_mean - cost) * rcp_fast(c_stdv + EPSF);
            float a_j = 1.f / (1.f + expf(-inv_temp * a_cost));
            float kc = logf(a_j + EPSF) - slogL[t];
            constL[t] = kc;
            aoutL[t] = 1.f / (1.f + expf(-a_j));
            float km = kc;
            km = fmaxf(km, __shfl_xor(km, 16)); km = fmaxf(km, __shfl_xor(km, 8));
            km = fmaxf(km, __shfl_xor(km, 4));  km = fmaxf(km, __shfl_xor(km, 2));
            km = fmaxf(km, __shfl_xor(km, 1));
            if (t == 0) KmaxL = km;
        }
    };

    // ---- pass 0: R uniform 1/32 -> Rw = ap/32; also build S1,S2 ----
    {
        float t1[16], s1[16], s2[16];
        #pragma unroll
        for (int d = 0; d < 16; ++d) { t1[d] = 0.f; s1[d] = 0.f; s2[d] = 0.f; }
        float rsum = 0.f;
        for (int j = 0; j < IPT; ++j) {
            const int i = iBase + j;
            float wa[16], ma[16];
            const float4* w4 = (const float4*)(Wg + ((size_t)((i << 5) + c) << 4));
            ((float4*)wa)[0] = w4[0]; ((float4*)wa)[1] = w4[1];
            ((float4*)wa)[2] = w4[2]; ((float4*)wa)[3] = w4[3];
            const float4* mp4 = (const float4*)(MpL + (i << 4));
            ((float4*)ma)[0] = mp4[0]; ((float4*)ma)[1] = mp4[1];
            ((float4*)ma)[2] = mp4[2]; ((float4*)ma)[3] = mp4[3];
            float rw = apL[i] * 0.03125f;
            rsum += rw;
            #pragma unroll
            for (int p = 0; p < 4; ++p)
                #pragma unroll
                for (int r = 0; r < 4; ++r) {
                    float acc = ma[p * 4 + 0] * wa[0 * 4 + r];
                    acc = fmaf(ma[p * 4 + 1], wa[1 * 4 + r], acc);
                    acc = fmaf(ma[p * 4 + 2], wa[2 * 4 + r], acc);
                    acc = fmaf(ma[p * 4 + 3], wa[3 * 4 + r], acc);
                    const int d = p * 4 + r;
                    t1[d] = fmaf(rw, acc, t1[d]);
                    s1[d] += acc;
                    s2[d] = fmaf(acc, acc, s2[d]);
                }
        }
        // combine partner half-waves (lane^32 shares c), then 32 lanes atomic
        rsum += __shfl_xor(rsum, 32);
        #pragma unroll
        for (int d = 0; d < 16; ++d) {
            t1[d] += __shfl_xor(t1[d], 32);
            s1[d] += __shfl_xor(s1[d], 32);
            s2[d] += __shfl_xor(s2[d], 32);
        }
        if ((t & 32) == 0) {
            atomicAdd(&RsumL[c], rsum);
            #pragma unroll
            for (int d = 0; d < 16; ++d) {
                atomicAdd(&T1L[c * ST + d], t1[d]);
                atomicAdd(&S1L[c * ST + d], s1[d]);
                atomicAdd(&S2L[c * ST + d], s2[d]);
            }
        }
        __syncthreads();
        statsA();
        __syncthreads();
        statsB(1.0f);   // it = 0
        __syncthreads();
    }

    // ---- passes 1,2: fused E-step (softmax over c, in-register) + M-step ----
    for (int it = 1; it < 3; ++it) {
        float Mreg[16], i2[16];
        #pragma unroll
        for (int d = 0; d < 16; ++d) {
            Mreg[d] = ML[c * ST + d];
            i2[d]   = I2L[c * ST + d] * L2E;   // log2-space quadratic
        }
        float Kc2 = (constL[c] - KmaxL) * L2E; // exp2 arg <= 0 always
        __syncthreads();                       // all reads done before re-zero
        if (t < NC * ST) T1L[t] = 0.f;
        if (t < NC) RsumL[t] = 0.f;
        __syncthreads();

        float t1[16];
        #pragma unroll
        for (int d = 0; d < 16; ++d) t1[d] = 0.f;
        float rsum = 0.f;
        for (int j = 0; j < IPT; ++j) {
            const int i = iBase + j;
            float wa[16], ma[16];
            const float4* w4 = (const float4*)(Wg + ((size_t)((i << 5) + c) << 4));
            ((float4*)wa)[0] = w4[0]; ((float4*)wa)[1] = w4[1];
            ((float4*)wa)[2] = w4[2]; ((float4*)wa)[3] = w4[3];
            const float4* mp4 = (const float4*)(MpL + (i << 4));
            ((float4*)ma)[0] = mp4[0]; ((float4*)ma)[1] = mp4[1];
            ((float4*)ma)[2] = mp4[2]; ((float4*)ma)[3] = mp4[3];
            float a_i = apL[i];
            float v[16];
            #pragma unroll
            for (int p = 0; p < 4; ++p)
                #pragma unroll
                for (int r = 0; r < 4; ++r) {
                    float acc = ma[p * 4 + 0] * wa[0 * 4 + r];
                    acc = fmaf(ma[p * 4 + 1], wa[1 * 4 + r], acc);
                    acc = fmaf(ma[p * 4 + 2], wa[2 * 4 + r], acc);
                    acc = fmaf(ma[p * 4 + 3], wa[3 * 4 + r], acc);
                    v[p * 4 + r] = acc;
                }
            float lp2 = Kc2;
            #pragma unroll
            for (int d = 0; d < 16; ++d) {
                float df = v[d] - Mreg[d];
                lp2 = fmaf(-df * df, i2[d], lp2);
            }
            float ex = exp2f(lp2);             // <= 1; denom >= e^-8: safe
            // softmax denominator: sum over the 32 caps of this half-wave
            float ssum = ex;
            ssum += __shfl_xor(ssum, 16); ssum += __shfl_xor(ssum, 8);
            ssum += __shfl_xor(ssum, 4);  ssum += __shfl_xor(ssum, 2);
            ssum += __shfl_xor(ssum, 1);
            float rw = ex * rcp_fast(ssum) * a_i;
            rsum += rw;
            #pragma unroll
            for (int d = 0; d < 16; ++d) t1[d] = fmaf(rw, v[d], t1[d]);
        }
        rsum += __shfl_xor(rsum, 32);
        #pragma unroll
        for (int d = 0; d < 16; ++d) t1[d] += __shfl_xor(t1[d], 32);
        if ((t & 32) == 0) {
            atomicAdd(&RsumL[c], rsum);
            #pragma unroll
            for (int d = 0; d < 16; ++d) atomicAdd(&T1L[c * ST + d], t1[d]);
        }
        __syncthreads();
        statsA();
        __syncthreads();
        statsB(1.0f + (float)it);   // inv_temp = 1 + it
        __syncthreads();
    }

    // ---- epilogue: out[b,ho,wo,c,0:16]=M, out[...,16]=sigmoid(a_j) ----
    // output stride per capsule is 17 == ST, so ML indexes line up directly.
    if (t < NC * 17) {
        int cc = t / 17;
        int e = t - cc * 17;
        float val = (e < 16) ? ML[t] : aoutL[cc];
        out[(size_t)bid * (NC * 17) + t] = val;
    }
}

extern "C" void kernel_launch(void* const* d_in, const int* in_sizes, int n_in,
                              void* d_out, int out_size, void* d_ws, size_t ws_size,
                              hipStream_t stream) {
    const float* x  = (const float*)d_in[0];
    const float* W  = (const float*)d_in[1];
    const float* bv = (const float*)d_in[2];
    const float* ba = (const float*)d_in[3];
    float* out = (float*)d_out;
    // grid = B*Ho*Wo = 2*12*12 = 288 positions, one block each
    caps_em_kernel<<<288, NTHREADS, 0, stream>>>(x, W, bv, ba, out);
}

// Round 6
// 186.684 us; speedup vs baseline: 1.7679x; 1.2208x over previous
//
#include <hip/hip_runtime.h>
#include <math.h>

// ConvolutionalCapsule with EM routing, fully fused: one block per output
// position (b,ho,wo). Votes V[i,c,d] (288x32x16 per position) are NEVER
// materialized: recomputed from LDS patch tile + L2-resident W each pass.
// Key algebraic facts:
//  - reference stdv uses Rsum (not Rw) => var = UNWEIGHTED sum_i (v-M)^2,
//    so S1=sum_i v, S2=sum_i v^2 are iteration-invariant (computed once).
//  - E-step softmax over 32 caps is shift-invariant; quad term in [0,8]
//    => subtracting per-pass Kmax = max_c Kc bounds exp2 args <= 0 with
//    denominator >= e^-8: NO per-i max reduction needed (5-shuffle chain
//    per j-iter instead of 10).
//  - cost = rsum * (16*beta_v + sum_d log(stdv+eps)): one d-reduction only.
// Round-6: back to the 512-thread no-spill shape (R0: VGPR=100, harness
// 208us = session best) + the algorithmic set proven correct in R3-R5:
//  - Kmax trick + exp2-space softmax
//  - parallel statsA (512 thr, one per (c,d)) + 32-thread statsB
//  - ST=17 reduction arrays: (17c+d)%32 bijective => conflict-free atomics
// Round 1-5 lesson (documented): 1024-thr workgroups are VGPR-capped at 64
// on this toolchain regardless of launch_bounds / waves_per_eu / LDS-forced
// 1-block-per-CU => ~40 regs spill => harness dur regressed 208->228. The
// 512-thr shape gets VGPR=100 spill-free by default.
// Thread map: c = t&31, isub = t>>5 (0..15), i = isub*18 + j. Half-wave
// shares i (broadcast LDS reads, contiguous 2KB W row reads).

#define EPSF 1e-7f
#define KKI 288
#define NC 32
#define NTHREADS 512
#define IPT 18          // KKI / 16 half-waves
#define ST 17           // padded stride: (17c+d)%32 bijective over c
#define L2E 1.4426950408889634f

__device__ __forceinline__ float rcp_fast(float v) { return __builtin_amdgcn_rcpf(v); }

__global__ __launch_bounds__(NTHREADS)
void caps_em_kernel(const float* __restrict__ x, const float* __restrict__ Wg,
                    const float* __restrict__ beta_v, const float* __restrict__ beta_a,
                    float* __restrict__ out)
{
    __shared__ float MpL[KKI * 16];   // patch poses
    __shared__ float apL[KKI];        // patch activations
    __shared__ float T1L[NC * ST];    // sum_i Rw*v      (per iteration)
    __shared__ float S1L[NC * ST];    // sum_i v         (iteration-invariant)
    __shared__ float S2L[NC * ST];    // sum_i v^2       (iteration-invariant)
    __shared__ float ML[NC * ST];     // M
    __shared__ float I2L[NC * ST];    // 0.5/var
    __shared__ float RsumL[NC];
    __shared__ float constL[NC];      // Kc = log(a_j+eps) - sum_d log(stdv+eps)
    __shared__ float slogL[NC];
    __shared__ float costL[NC];
    __shared__ float aoutL[NC];       // sigmoid(a_j)
    __shared__ float KmaxL;           // max_c Kc

    const int t = threadIdx.x;
    const int bid = blockIdx.x;           // b*144 + ho*12 + wo
    const int b = bid / 144;
    const int rem = bid - b * 144;
    const int ho = rem / 12;
    const int wo = rem - ho * 12;

    const int c = t & 31;
    const int isub = t >> 5;              // 0..15
    const int iBase = isub * IPT;

    // ---- stage patch tile: Mp[i][0..15], ap[i], i = p*32+cin, p = di*3+dj ----
    for (int idx = t; idx < KKI * 17; idx += NTHREADS) {
        int i = idx / 17;
        int e = idx - i * 17;
        int p = i >> 5, cin = i & 31;
        int di = p / 3, dj = p - di * 3;
        float vx = x[(((b * 14 + (ho + di)) * 14 + (wo + dj)) * 32 + cin) * 17 + e];
        if (e < 16) MpL[i * 16 + e] = vx; else apL[i] = vx;
    }
    for (int idx = t; idx < NC * ST; idx += NTHREADS) { T1L[idx] = 0.f; S1L[idx] = 0.f; S2L[idx] = 0.f; }
    if (t < NC) RsumL[t] = 0.f;
    __syncthreads();

    // stats A: all 512 threads, one per (capsule cc = t>>4, dim d = t&15);
    // d occupies lane bits 0-3 so the slog reduction is a 4-step shfl_xor.
    auto statsA = [&]() {
        const int cc = t >> 4, d = t & 15;
        float rsum = RsumL[cc];
        float m = T1L[cc * ST + d] * rcp_fast(rsum);
        float var = S2L[cc * ST + d] - 2.f * m * S1L[cc * ST + d] + 288.f * m * m;
        var = fmaxf(var, 0.f);
        float lg = logf(sqrtf(var) + EPSF);
        ML[cc * ST + d] = m;
        I2L[cc * ST + d] = 0.5f * rcp_fast(var);
        float sl = lg;
        sl += __shfl_xor(sl, 1); sl += __shfl_xor(sl, 2);
        sl += __shfl_xor(sl, 4); sl += __shfl_xor(sl, 8);
        if (d == 0) {
            slogL[cc] = sl;
            costL[cc] = rsum * (16.f * beta_v[cc] + sl);
        }
    };
    // stats B: cross-capsule mean/std + activation + Kmax (32 threads).
    auto statsB = [&](float inv_temp) {
        if (t < 32) {
            float cost = costL[t];
            float csum = cost;
            csum += __shfl_xor(csum, 16); csum += __shfl_xor(csum, 8);
            csum += __shfl_xor(csum, 4);  csum += __shfl_xor(csum, 2);
            csum += __shfl_xor(csum, 1);
            float c_mean = csum * 0.03125f;
            float diff = cost - c_mean;
            float dsq = diff * diff;
            dsq += __shfl_xor(dsq, 16); dsq += __shfl_xor(dsq, 8);
            dsq += __shfl_xor(dsq, 4);  dsq += __shfl_xor(dsq, 2);
            dsq += __shfl_xor(dsq, 1);
            float c_stdv = sqrtf(dsq * 0.03125f);
            float a_cost = beta_a[t] + (c_mean - cost) * rcp_fast(c_stdv + EPSF);
            float a_j = 1.f / (1.f + expf(-inv_temp * a_cost));
            float kc = logf(a_j + EPSF) - slogL[t];
            constL[t] = kc;
            aoutL[t] = 1.f / (1.f + expf(-a_j));
            float km = kc;
            km = fmaxf(km, __shfl_xor(km, 16)); km = fmaxf(km, __shfl_xor(km, 8));
            km = fmaxf(km, __shfl_xor(km, 4));  km = fmaxf(km, __shfl_xor(km, 2));
            km = fmaxf(km, __shfl_xor(km, 1));
            if (t == 0) KmaxL = km;
        }
    };

    // ---- pass 0: R uniform 1/32 -> Rw = ap/32; also build S1,S2 ----
    {
        float t1[16], s1[16], s2[16];
        #pragma unroll
        for (int d = 0; d < 16; ++d) { t1[d] = 0.f; s1[d] = 0.f; s2[d] = 0.f; }
        float rsum = 0.f;
        for (int j = 0; j < IPT; ++j) {
            const int i = iBase + j;
            float wa[16], ma[16];
            const float4* w4 = (const float4*)(Wg + ((size_t)((i << 5) + c) << 4));
            ((float4*)wa)[0] = w4[0]; ((float4*)wa)[1] = w4[1];
            ((float4*)wa)[2] = w4[2]; ((float4*)wa)[3] = w4[3];
            const float4* mp4 = (const float4*)(MpL + (i << 4));
            ((float4*)ma)[0] = mp4[0]; ((float4*)ma)[1] = mp4[1];
            ((float4*)ma)[2] = mp4[2]; ((float4*)ma)[3] = mp4[3];
            float rw = apL[i] * 0.03125f;
            rsum += rw;
            #pragma unroll
            for (int p = 0; p < 4; ++p)
                #pragma unroll
                for (int r = 0; r < 4; ++r) {
                    float acc = ma[p * 4 + 0] * wa[0 * 4 + r];
                    acc = fmaf(ma[p * 4 + 1], wa[1 * 4 + r], acc);
                    acc = fmaf(ma[p * 4 + 2], wa[2 * 4 + r], acc);
                    acc = fmaf(ma[p * 4 + 3], wa[3 * 4 + r], acc);
                    const int d = p * 4 + r;
                    t1[d] = fmaf(rw, acc, t1[d]);
                    s1[d] += acc;
                    s2[d] = fmaf(acc, acc, s2[d]);
                }
        }
        // combine partner half-waves (lane^32 shares c), then 32 lanes atomic
        rsum += __shfl_xor(rsum, 32);
        #pragma unroll
        for (int d = 0; d < 16; ++d) {
            t1[d] += __shfl_xor(t1[d], 32);
            s1[d] += __shfl_xor(s1[d], 32);
            s2[d] += __shfl_xor(s2[d], 32);
        }
        if ((t & 32) == 0) {
            atomicAdd(&RsumL[c], rsum);
            #pragma unroll
            for (int d = 0; d < 16; ++d) {
                atomicAdd(&T1L[c * ST + d], t1[d]);
                atomicAdd(&S1L[c * ST + d], s1[d]);
                atomicAdd(&S2L[c * ST + d], s2[d]);
            }
        }
        __syncthreads();
        statsA();
        __syncthreads();
        statsB(1.0f);   // it = 0
        __syncthreads();
    }

    // ---- passes 1,2: fused E-step (softmax over c, in-register) + M-step ----
    for (int it = 1; it < 3; ++it) {
        float Mreg[16], i2[16];
        #pragma unroll
        for (int d = 0; d < 16; ++d) {
            Mreg[d] = ML[c * ST + d];
            i2[d]   = I2L[c * ST + d] * L2E;   // log2-space quadratic
        }
        float Kc2 = (constL[c] - KmaxL) * L2E; // exp2 arg <= 0 always
        __syncthreads();                       // all reads done before re-zero
        for (int idx = t; idx < NC * ST; idx += NTHREADS) T1L[idx] = 0.f;
        if (t < NC) RsumL[t] = 0.f;
        __syncthreads();

        float t1[16];
        #pragma unroll
        for (int d = 0; d < 16; ++d) t1[d] = 0.f;
        float rsum = 0.f;
        for (int j = 0; j < IPT; ++j) {
            const int i = iBase + j;
            float wa[16], ma[16];
            const float4* w4 = (const float4*)(Wg + ((size_t)((i << 5) + c) << 4));
            ((float4*)wa)[0] = w4[0]; ((float4*)wa)[1] = w4[1];
            ((float4*)wa)[2] = w4[2]; ((float4*)wa)[3] = w4[3];
            const float4* mp4 = (const float4*)(MpL + (i << 4));
            ((float4*)ma)[0] = mp4[0]; ((float4*)ma)[1] = mp4[1];
            ((float4*)ma)[2] = mp4[2]; ((float4*)ma)[3] = mp4[3];
            float a_i = apL[i];
            float v[16];
            #pragma unroll
            for (int p = 0; p < 4; ++p)
                #pragma unroll
                for (int r = 0; r < 4; ++r) {
                    float acc = ma[p * 4 + 0] * wa[0 * 4 + r];
                    acc = fmaf(ma[p * 4 + 1], wa[1 * 4 + r], acc);
                    acc = fmaf(ma[p * 4 + 2], wa[2 * 4 + r], acc);
                    acc = fmaf(ma[p * 4 + 3], wa[3 * 4 + r], acc);
                    v[p * 4 + r] = acc;
                }
            float lp2 = Kc2;
            #pragma unroll
            for (int d = 0; d < 16; ++d) {
                float df = v[d] - Mreg[d];
                lp2 = fmaf(-df * df, i2[d], lp2);
            }
            float ex = exp2f(lp2);             // <= 1; denom >= e^-8: safe
            // softmax denominator: sum over the 32 caps of this half-wave
            float ssum = ex;
            ssum += __shfl_xor(ssum, 16); ssum += __shfl_xor(ssum, 8);
            ssum += __shfl_xor(ssum, 4);  ssum += __shfl_xor(ssum, 2);
            ssum += __shfl_xor(ssum, 1);
            float rw = ex * rcp_fast(ssum) * a_i;
            rsum += rw;
            #pragma unroll
            for (int d = 0; d < 16; ++d) t1[d] = fmaf(rw, v[d], t1[d]);
        }
        rsum += __shfl_xor(rsum, 32);
        #pragma unroll
        for (int d = 0; d < 16; ++d) t1[d] += __shfl_xor(t1[d], 32);
        if ((t & 32) == 0) {
            atomicAdd(&RsumL[c], rsum);
            #pragma unroll
            for (int d = 0; d < 16; ++d) atomicAdd(&T1L[c * ST + d], t1[d]);
        }
        __syncthreads();
        statsA();
        __syncthreads();
        statsB(1.0f + (float)it);   // inv_temp = 1 + it
        __syncthreads();
    }

    // ---- epilogue: out[b,ho,wo,c,0:16]=M, out[...,16]=sigmoid(a_j) ----
    // output stride per capsule is 17 == ST, so ML indexes line up directly.
    for (int idx = t; idx < NC * 17; idx += NTHREADS) {
        int cc = idx / 17;
        int e = idx - cc * 17;
        float val = (e < 16) ? ML[idx] : aoutL[cc];
        out[(size_t)bid * (NC * 17) + idx] = val;
    }
}

extern "C" void kernel_launch(void* const* d_in, const int* in_sizes, int n_in,
                              void* d_out, int out_size, void* d_ws, size_t ws_size,
                              hipStream_t stream) {
    const float* x  = (const float*)d_in[0];
    const float* W  = (const float*)d_in[1];
    const float* bv = (const float*)d_in[2];
    const float* ba = (const float*)d_in[3];
    float* out = (float*)d_out;
    // grid = B*Ho*Wo = 2*12*12 = 288 positions, one block each
    caps_em_kernel<<<288, NTHREADS, 0, stream>>>(x, W, bv, ba, out);
}

// Round 7
// 180.367 us; speedup vs baseline: 1.8298x; 1.0350x over previous
//
#include <hip/hip_runtime.h>
#include <math.h>

// ConvolutionalCapsule with EM routing, fully fused: one block per output
// position (b,ho,wo). Votes V[i,c,d] (288x32x16 per position) are NEVER
// materialized: recomputed from LDS patch tile + L2-resident W each pass.
// Key algebraic facts:
//  - reference stdv uses Rsum (not Rw) => var = UNWEIGHTED sum_i (v-M)^2,
//    so S1=sum_i v, S2=sum_i v^2 are iteration-invariant (computed once).
//  - E-step softmax over 32 caps is shift-invariant; quad term in [0,8]
//    => subtracting per-pass Kmax = max_c Kc bounds exp2 args <= 0 with
//    denominator >= e^-8: NO per-i max reduction needed.
//  - cost = rsum * (16*beta_v + sum_d log(stdv+eps)): one d-reduction only.
// Round-7 (vs round-6 PASSED, harness 186.7us, rocprof 137us):
//  - ONLY change: cross-lane reduces use DPP for the within-16-lane steps
//    (masks 1,2 via quad_perm; 4,8 via row_ror — rotation is valid for a
//    commutative sum) + a single __shfl_xor(16) for the cross-row step.
//    R6 evidence: removing 5 of 10 shuffles/iter bought ~48us => the
//    remaining 5-deep ds_swizzle chain is the dominant exposed latency;
//    DPP is VALU-pipe (~8cy vs ~350cy effective per link).
//    (R2's DPP failure was confounded with a lane remap + permlane32_swap;
//    both remain excluded. Lane map here is byte-identical to R6.)
// Round 1-5 lesson: 1024-thr workgroups are VGPR-capped at 64 on this
// toolchain (launch_bounds / waves_per_eu / LDS-pad all failed to lift it)
// => spills => harness regression. 512-thr gets VGPR~76-100 spill-free.
// Thread map: c = t&31, isub = t>>5 (0..15), i = isub*18 + j. Half-wave
// shares i (broadcast LDS reads, contiguous 2KB W row reads).

#define EPSF 1e-7f
#define KKI 288
#define NC 32
#define NTHREADS 512
#define IPT 18          // KKI / 16 half-waves
#define ST 17           // padded stride: (17c+d)%32 bijective over c
#define L2E 1.4426950408889634f

__device__ __forceinline__ float rcp_fast(float v) { return __builtin_amdgcn_rcpf(v); }

// DPP-based cross-lane (VALU pipe; vs ds_swizzle ~hundreds of cycles)
template <int CTRL>
__device__ __forceinline__ float dpp_mov_f(float x) {
    return __int_as_float(__builtin_amdgcn_update_dpp(
        0, __float_as_int(x), CTRL, 0xF, 0xF, true));
}
// sum over each 16-lane row: xor1, xor2 (quad_perm), then two quad
// rotations (complete for commutative sum: after quads hold quad-sums,
// ror:4 adds the next quad, ror:8 adds the remaining two).
__device__ __forceinline__ float row_sum16(float x) {
    x += dpp_mov_f<0xB1>(x);    // quad_perm [1,0,3,2]  (xor 1)
    x += dpp_mov_f<0x4E>(x);    // quad_perm [2,3,0,1]  (xor 2)
    x += dpp_mov_f<0x124>(x);   // row_ror:4
    x += dpp_mov_f<0x128>(x);   // row_ror:8
    return x;
}
__device__ __forceinline__ float row_max16(float x) {
    x = fmaxf(x, dpp_mov_f<0xB1>(x));
    x = fmaxf(x, dpp_mov_f<0x4E>(x));
    x = fmaxf(x, dpp_mov_f<0x124>(x));
    x = fmaxf(x, dpp_mov_f<0x128>(x));
    return x;
}

__global__ __launch_bounds__(NTHREADS)
void caps_em_kernel(const float* __restrict__ x, const float* __restrict__ Wg,
                    const float* __restrict__ beta_v, const float* __restrict__ beta_a,
                    float* __restrict__ out)
{
    __shared__ float MpL[KKI * 16];   // patch poses
    __shared__ float apL[KKI];        // patch activations
    __shared__ float T1L[NC * ST];    // sum_i Rw*v      (per iteration)
    __shared__ float S1L[NC * ST];    // sum_i v         (iteration-invariant)
    __shared__ float S2L[NC * ST];    // sum_i v^2       (iteration-invariant)
    __shared__ float ML[NC * ST];     // M
    __shared__ float I2L[NC * ST];    // 0.5/var
    __shared__ float RsumL[NC];
    __shared__ float constL[NC];      // Kc = log(a_j+eps) - sum_d log(stdv+eps)
    __shared__ float slogL[NC];
    __shared__ float costL[NC];
    __shared__ float aoutL[NC];       // sigmoid(a_j)
    __shared__ float KmaxL;           // max_c Kc

    const int t = threadIdx.x;
    const int bid = blockIdx.x;           // b*144 + ho*12 + wo
    const int b = bid / 144;
    const int rem = bid - b * 144;
    const int ho = rem / 12;
    const int wo = rem - ho * 12;

    const int c = t & 31;
    const int isub = t >> 5;              // 0..15
    const int iBase = isub * IPT;

    // ---- stage patch tile: Mp[i][0..15], ap[i], i = p*32+cin, p = di*3+dj ----
    for (int idx = t; idx < KKI * 17; idx += NTHREADS) {
        int i = idx / 17;
        int e = idx - i * 17;
        int p = i >> 5, cin = i & 31;
        int di = p / 3, dj = p - di * 3;
        float vx = x[(((b * 14 + (ho + di)) * 14 + (wo + dj)) * 32 + cin) * 17 + e];
        if (e < 16) MpL[i * 16 + e] = vx; else apL[i] = vx;
    }
    for (int idx = t; idx < NC * ST; idx += NTHREADS) { T1L[idx] = 0.f; S1L[idx] = 0.f; S2L[idx] = 0.f; }
    if (t < NC) RsumL[t] = 0.f;
    __syncthreads();

    // stats A: all 512 threads, one per (capsule cc = t>>4, dim d = t&15);
    // d occupies lane bits 0-3 so the slog reduction is a pure-DPP row sum.
    auto statsA = [&]() {
        const int cc = t >> 4, d = t & 15;
        float rsum = RsumL[cc];
        float m = T1L[cc * ST + d] * rcp_fast(rsum);
        float var = S2L[cc * ST + d] - 2.f * m * S1L[cc * ST + d] + 288.f * m * m;
        var = fmaxf(var, 0.f);
        float lg = logf(sqrtf(var) + EPSF);
        ML[cc * ST + d] = m;
        I2L[cc * ST + d] = 0.5f * rcp_fast(var);
        float sl = row_sum16(lg);
        if (d == 0) {
            slogL[cc] = sl;
            costL[cc] = rsum * (16.f * beta_v[cc] + sl);
        }
    };
    // stats B: cross-capsule mean/std + activation + Kmax (32 threads).
    auto statsB = [&](float inv_temp) {
        if (t < 32) {
            float cost = costL[t];
            float csum = row_sum16(cost); csum += __shfl_xor(csum, 16);
            float c_mean = csum * 0.03125f;
            float diff = cost - c_mean;
            float dsq = row_sum16(diff * diff); dsq += __shfl_xor(dsq, 16);
            float c_stdv = sqrtf(dsq * 0.03125f);
            float a_cost = beta_a[t] + (c_mean - cost) * rcp_fast(c_stdv + EPSF);
            float a_j = 1.f / (1.f + expf(-inv_temp * a_cost));
            float kc = logf(a_j + EPSF) - slogL[t];
            constL[t] = kc;
            aoutL[t] = 1.f / (1.f + expf(-a_j));
            float km = row_max16(kc); km = fmaxf(km, __shfl_xor(km, 16));
            if (t == 0) KmaxL = km;
        }
    };

    // ---- pass 0: R uniform 1/32 -> Rw = ap/32; also build S1,S2 ----
    {
        float t1[16], s1[16], s2[16];
        #pragma unroll
        for (int d = 0; d < 16; ++d) { t1[d] = 0.f; s1[d] = 0.f; s2[d] = 0.f; }
        float rsum = 0.f;
        for (int j = 0; j < IPT; ++j) {
            const int i = iBase + j;
            float wa[16], ma[16];
            const float4* w4 = (const float4*)(Wg + ((size_t)((i << 5) + c) << 4));
            ((float4*)wa)[0] = w4[0]; ((float4*)wa)[1] = w4[1];
            ((float4*)wa)[2] = w4[2]; ((float4*)wa)[3] = w4[3];
            const float4* mp4 = (const float4*)(MpL + (i << 4));
            ((float4*)ma)[0] = mp4[0]; ((float4*)ma)[1] = mp4[1];
            ((float4*)ma)[2] = mp4[2]; ((float4*)ma)[3] = mp4[3];
            float rw = apL[i] * 0.03125f;
            rsum += rw;
            #pragma unroll
            for (int p = 0; p < 4; ++p)
                #pragma unroll
                for (int r = 0; r < 4; ++r) {
                    float acc = ma[p * 4 + 0] * wa[0 * 4 + r];
                    acc = fmaf(ma[p * 4 + 1], wa[1 * 4 + r], acc);
                    acc = fmaf(ma[p * 4 + 2], wa[2 * 4 + r], acc);
                    acc = fmaf(ma[p * 4 + 3], wa[3 * 4 + r], acc);
                    const int d = p * 4 + r;
                    t1[d] = fmaf(rw, acc, t1[d]);
                    s1[d] += acc;
                    s2[d] = fmaf(acc, acc, s2[d]);
                }
        }
        // combine partner half-waves (lane^32 shares c), then 32 lanes atomic
        rsum += __shfl_xor(rsum, 32);
        #pragma unroll
        for (int d = 0; d < 16; ++d) {
            t1[d] += __shfl_xor(t1[d], 32);
            s1[d] += __shfl_xor(s1[d], 32);
            s2[d] += __shfl_xor(s2[d], 32);
        }
        if ((t & 32) == 0) {
            atomicAdd(&RsumL[c], rsum);
            #pragma unroll
            for (int d = 0; d < 16; ++d) {
                atomicAdd(&T1L[c * ST + d], t1[d]);
                atomicAdd(&S1L[c * ST + d], s1[d]);
                atomicAdd(&S2L[c * ST + d], s2[d]);
            }
        }
        __syncthreads();
        statsA();
        __syncthreads();
        statsB(1.0f);   // it = 0
        __syncthreads();
    }

    // ---- passes 1,2: fused E-step (softmax over c, in-register) + M-step ----
    for (int it = 1; it < 3; ++it) {
        float Mreg[16], i2[16];
        #pragma unroll
        for (int d = 0; d < 16; ++d) {
            Mreg[d] = ML[c * ST + d];
            i2[d]   = I2L[c * ST + d] * L2E;   // log2-space quadratic
        }
        float Kc2 = (constL[c] - KmaxL) * L2E; // exp2 arg <= 0 always
        __syncthreads();                       // all reads done before re-zero
        for (int idx = t; idx < NC * ST; idx += NTHREADS) T1L[idx] = 0.f;
        if (t < NC) RsumL[t] = 0.f;
        __syncthreads();

        float t1[16];
        #pragma unroll
        for (int d = 0; d < 16; ++d) t1[d] = 0.f;
        float rsum = 0.f;
        for (int j = 0; j < IPT; ++j) {
            const int i = iBase + j;
            float wa[16], ma[16];
            const float4* w4 = (const float4*)(Wg + ((size_t)((i << 5) + c) << 4));
            ((float4*)wa)[0] = w4[0]; ((float4*)wa)[1] = w4[1];
            ((float4*)wa)[2] = w4[2]; ((float4*)wa)[3] = w4[3];
            const float4* mp4 = (const float4*)(MpL + (i << 4));
            ((float4*)ma)[0] = mp4[0]; ((float4*)ma)[1] = mp4[1];
            ((float4*)ma)[2] = mp4[2]; ((float4*)ma)[3] = mp4[3];
            float a_i = apL[i];
            float v[16];
            #pragma unroll
            for (int p = 0; p < 4; ++p)
                #pragma unroll
                for (int r = 0; r < 4; ++r) {
                    float acc = ma[p * 4 + 0] * wa[0 * 4 + r];
                    acc = fmaf(ma[p * 4 + 1], wa[1 * 4 + r], acc);
                    acc = fmaf(ma[p * 4 + 2], wa[2 * 4 + r], acc);
                    acc = fmaf(ma[p * 4 + 3], wa[3 * 4 + r], acc);
                    v[p * 4 + r] = acc;
                }
            float lp2 = Kc2;
            #pragma unroll
            for (int d = 0; d < 16; ++d) {
                float df = v[d] - Mreg[d];
                lp2 = fmaf(-df * df, i2[d], lp2);
            }
            float ex = exp2f(lp2);             // <= 1; denom >= e^-8: safe
            // softmax denominator over the 32 caps of this half-wave:
            // DPP row sum (lane bits 0-3) + one cross-row shfl (bit 4)
            float ssum = row_sum16(ex);
            ssum += __shfl_xor(ssum, 16);
            float rw = ex * rcp_fast(ssum) * a_i;
            rsum += rw;
            #pragma unroll
            for (int d = 0; d < 16; ++d) t1[d] = fmaf(rw, v[d], t1[d]);
        }
        rsum += __shfl_xor(rsum, 32);
        #pragma unroll
        for (int d = 0; d < 16; ++d) t1[d] += __shfl_xor(t1[d], 32);
        if ((t & 32) == 0) {
            atomicAdd(&RsumL[c], rsum);
            #pragma unroll
            for (int d = 0; d < 16; ++d) atomicAdd(&T1L[c * ST + d], t1[d]);
        }
        __syncthreads();
        statsA();
        __syncthreads();
        statsB(1.0f + (float)it);   // inv_temp = 1 + it
        __syncthreads();
    }

    // ---- epilogue: out[b,ho,wo,c,0:16]=M, out[...,16]=sigmoid(a_j) ----
    // output stride per capsule is 17 == ST, so ML indexes line up directly.
    for (int idx = t; idx < NC * 17; idx += NTHREADS) {
        int cc = idx / 17;
        int e = idx - cc * 17;
        float val = (e < 16) ? ML[idx] : aoutL[cc];
        out[(size_t)bid * (NC * 17) + idx] = val;
    }
}

extern "C" void kernel_launch(void* const* d_in, const int* in_sizes, int n_in,
                              void* d_out, int out_size, void* d_ws, size_t ws_size,
                              hipStream_t stream) {
    const float* x  = (const float*)d_in[0];
    const float* W  = (const float*)d_in[1];
    const float* bv = (const float*)d_in[2];
    const float* ba = (const float*)d_in[3];
    float* out = (float*)d_out;
    // grid = B*Ho*Wo = 2*12*12 = 288 positions, one block each
    caps_em_kernel<<<288, NTHREADS, 0, stream>>>(x, W, bv, ba, out);
}

// Round 8
// 179.691 us; speedup vs baseline: 1.8366x; 1.0038x over previous
//
#include <hip/hip_runtime.h>
#include <math.h>

// ConvolutionalCapsule with EM routing, fully fused: one block per output
// position (b,ho,wo). Votes V[i,c,d] (288x32x16 per position) are NEVER
// materialized: recomputed from LDS patch tile + L2-resident W each pass.
// Key algebraic facts:
//  - reference stdv uses Rsum (not Rw) => var = UNWEIGHTED sum_i (v-M)^2,
//    so S1=sum_i v, S2=sum_i v^2 are iteration-invariant (computed once).
//  - E-step softmax over 32 caps is shift-invariant; quad term in [0,8]
//    => subtracting per-pass Kmax = max_c Kc bounds exp2 args <= 0 with
//    denominator >= e^-8: NO per-i max reduction needed.
//  - cost = rsum * (16*beta_v + sum_d log(stdv+eps)): one d-reduction only.
// Round-8 (vs round-7 PASSED, harness 180.4us, rocprof 129us):
//  - MAIN change: A/B software pipeline of the W fragment. R7 counters
//    (VALUBusy 16.7%, 5.7K cy/iter vs ~650cy chain, VGPR=72 of a free 128
//    budget) say the compiler serializes the four W dwordx4 loads and has
//    no cross-iteration ILP. Explicit prefetch of W[j+1] into a ping-pong
//    register pair overlaps L2 latency with compute, spending free VGPR
//    headroom (>64 already caps occupancy at 4 waves/SIMD; 128 is free).
//  - lp2 chain split into two 8-deep partials (halves dep latency).
//  - statsA pre-scales I2L by log2(e) (16 fewer VALU per E-pass prologue).
// Round 1-5 lesson: 1024-thr workgroups are VGPR-capped at 64 on this
// toolchain => spills => regression. 512-thr gets ~72-128 spill-free.
// R6/R7 lessons: parallel stats + Kmax + DPP row reduce all proven.
// Thread map: c = t&31, isub = t>>5 (0..15), i = isub*18 + j. Half-wave
// shares i (broadcast LDS reads, contiguous 2KB W row reads).

#define EPSF 1e-7f
#define KKI 288
#define NC 32
#define NTHREADS 512
#define IPT 18          // KKI / 16 half-waves (even: A/B pipeline is clean)
#define ST 17           // padded stride: (17c+d)%32 bijective over c
#define L2E 1.4426950408889634f

__device__ __forceinline__ float rcp_fast(float v) { return __builtin_amdgcn_rcpf(v); }

// DPP-based cross-lane (VALU pipe; proven R7)
template <int CTRL>
__device__ __forceinline__ float dpp_mov_f(float x) {
    return __int_as_float(__builtin_amdgcn_update_dpp(
        0, __float_as_int(x), CTRL, 0xF, 0xF, true));
}
__device__ __forceinline__ float row_sum16(float x) {
    x += dpp_mov_f<0xB1>(x);    // quad_perm xor1
    x += dpp_mov_f<0x4E>(x);    // quad_perm xor2
    x += dpp_mov_f<0x124>(x);   // row_ror:4
    x += dpp_mov_f<0x128>(x);   // row_ror:8
    return x;
}
__device__ __forceinline__ float row_max16(float x) {
    x = fmaxf(x, dpp_mov_f<0xB1>(x));
    x = fmaxf(x, dpp_mov_f<0x4E>(x));
    x = fmaxf(x, dpp_mov_f<0x124>(x));
    x = fmaxf(x, dpp_mov_f<0x128>(x));
    return x;
}

__global__ __launch_bounds__(NTHREADS)
void caps_em_kernel(const float* __restrict__ x, const float* __restrict__ Wg,
                    const float* __restrict__ beta_v, const float* __restrict__ beta_a,
                    float* __restrict__ out)
{
    __shared__ float MpL[KKI * 16];   // patch poses
    __shared__ float apL[KKI];        // patch activations
    __shared__ float T1L[NC * ST];    // sum_i Rw*v      (per iteration)
    __shared__ float S1L[NC * ST];    // sum_i v         (iteration-invariant)
    __shared__ float S2L[NC * ST];    // sum_i v^2       (iteration-invariant)
    __shared__ float ML[NC * ST];     // M
    __shared__ float I2L[NC * ST];    // 0.5/var * log2(e)   (pre-scaled)
    __shared__ float RsumL[NC];
    __shared__ float constL[NC];      // Kc = log(a_j+eps) - sum_d log(stdv+eps)
    __shared__ float slogL[NC];
    __shared__ float costL[NC];
    __shared__ float aoutL[NC];       // sigmoid(a_j)
    __shared__ float KmaxL;           // max_c Kc

    const int t = threadIdx.x;
    const int bid = blockIdx.x;           // b*144 + ho*12 + wo
    const int b = bid / 144;
    const int rem = bid - b * 144;
    const int ho = rem / 12;
    const int wo = rem - ho * 12;

    const int c = t & 31;
    const int isub = t >> 5;              // 0..15
    const int iBase = isub * IPT;

    // ---- stage patch tile: Mp[i][0..15], ap[i], i = p*32+cin, p = di*3+dj ----
    for (int idx = t; idx < KKI * 17; idx += NTHREADS) {
        int i = idx / 17;
        int e = idx - i * 17;
        int p = i >> 5, cin = i & 31;
        int di = p / 3, dj = p - di * 3;
        float vx = x[(((b * 14 + (ho + di)) * 14 + (wo + dj)) * 32 + cin) * 17 + e];
        if (e < 16) MpL[i * 16 + e] = vx; else apL[i] = vx;
    }
    for (int idx = t; idx < NC * ST; idx += NTHREADS) { T1L[idx] = 0.f; S1L[idx] = 0.f; S2L[idx] = 0.f; }
    if (t < NC) RsumL[t] = 0.f;
    __syncthreads();

    // W fragment load: 64B for (i, c) as 4x float4
    auto loadW = [&](float (&wa)[16], int i) {
        const float4* w4 = (const float4*)(Wg + ((size_t)((i << 5) + c) << 4));
        ((float4*)wa)[0] = w4[0]; ((float4*)wa)[1] = w4[1];
        ((float4*)wa)[2] = w4[2]; ((float4*)wa)[3] = w4[3];
    };

    // stats A: all 512 threads, one per (capsule cc = t>>4, dim d = t&15);
    // d occupies lane bits 0-3 so the slog reduction is a pure-DPP row sum.
    auto statsA = [&]() {
        const int cc = t >> 4, d = t & 15;
        float rsum = RsumL[cc];
        float m = T1L[cc * ST + d] * rcp_fast(rsum);
        float var = S2L[cc * ST + d] - 2.f * m * S1L[cc * ST + d] + 288.f * m * m;
        var = fmaxf(var, 0.f);
        float lg = logf(sqrtf(var) + EPSF);
        ML[cc * ST + d] = m;
        I2L[cc * ST + d] = 0.5f * L2E * rcp_fast(var);   // pre-scaled by log2e
        float sl = row_sum16(lg);
        if (d == 0) {
            slogL[cc] = sl;
            costL[cc] = rsum * (16.f * beta_v[cc] + sl);
        }
    };
    // stats B: cross-capsule mean/std + activation + Kmax (32 threads).
    auto statsB = [&](float inv_temp) {
        if (t < 32) {
            float cost = costL[t];
            float csum = row_sum16(cost); csum += __shfl_xor(csum, 16);
            float c_mean = csum * 0.03125f;
            float diff = cost - c_mean;
            float dsq = row_sum16(diff * diff); dsq += __shfl_xor(dsq, 16);
            float c_stdv = sqrtf(dsq * 0.03125f);
            float a_cost = beta_a[t] + (c_mean - cost) * rcp_fast(c_stdv + EPSF);
            float a_j = 1.f / (1.f + expf(-inv_temp * a_cost));
            float kc = logf(a_j + EPSF) - slogL[t];
            constL[t] = kc;
            aoutL[t] = 1.f / (1.f + expf(-a_j));
            float km = row_max16(kc); km = fmaxf(km, __shfl_xor(km, 16));
            if (t == 0) KmaxL = km;
        }
    };

    // ---- pass 0: R uniform 1/32 -> Rw = ap/32; also build S1,S2 ----
    {
        float t1[16], s1[16], s2[16];
        #pragma unroll
        for (int d = 0; d < 16; ++d) { t1[d] = 0.f; s1[d] = 0.f; s2[d] = 0.f; }
        float rsum = 0.f;

        auto step0 = [&](float (&wa)[16], int i) {
            float ma[16];
            const float4* mp4 = (const float4*)(MpL + (i << 4));
            ((float4*)ma)[0] = mp4[0]; ((float4*)ma)[1] = mp4[1];
            ((float4*)ma)[2] = mp4[2]; ((float4*)ma)[3] = mp4[3];
            float rw = apL[i] * 0.03125f;
            rsum += rw;
            #pragma unroll
            for (int p = 0; p < 4; ++p)
                #pragma unroll
                for (int r = 0; r < 4; ++r) {
                    float acc = ma[p * 4 + 0] * wa[0 * 4 + r];
                    acc = fmaf(ma[p * 4 + 1], wa[1 * 4 + r], acc);
                    acc = fmaf(ma[p * 4 + 2], wa[2 * 4 + r], acc);
                    acc = fmaf(ma[p * 4 + 3], wa[3 * 4 + r], acc);
                    const int d = p * 4 + r;
                    t1[d] = fmaf(rw, acc, t1[d]);
                    s1[d] += acc;
                    s2[d] = fmaf(acc, acc, s2[d]);
                }
        };

        float waA[16], waB[16];
        loadW(waA, iBase);
        for (int j = 0; j < IPT; j += 2) {
            loadW(waB, iBase + j + 1);
            step0(waA, iBase + j);
            if (j + 2 < IPT) loadW(waA, iBase + j + 2);
            step0(waB, iBase + j + 1);
        }

        // combine partner half-waves (lane^32 shares c), then 32 lanes atomic
        rsum += __shfl_xor(rsum, 32);
        #pragma unroll
        for (int d = 0; d < 16; ++d) {
            t1[d] += __shfl_xor(t1[d], 32);
            s1[d] += __shfl_xor(s1[d], 32);
            s2[d] += __shfl_xor(s2[d], 32);
        }
        if ((t & 32) == 0) {
            atomicAdd(&RsumL[c], rsum);
            #pragma unroll
            for (int d = 0; d < 16; ++d) {
                atomicAdd(&T1L[c * ST + d], t1[d]);
                atomicAdd(&S1L[c * ST + d], s1[d]);
                atomicAdd(&S2L[c * ST + d], s2[d]);
            }
        }
        __syncthreads();
        statsA();
        __syncthreads();
        statsB(1.0f);   // it = 0
        __syncthreads();
    }

    // ---- passes 1,2: fused E-step (softmax over c, in-register) + M-step ----
    for (int it = 1; it < 3; ++it) {
        float Mreg[16], i2[16];
        #pragma unroll
        for (int d = 0; d < 16; ++d) {
            Mreg[d] = ML[c * ST + d];
            i2[d]   = I2L[c * ST + d];         // already log2-space scaled
        }
        float Kc2 = (constL[c] - KmaxL) * L2E; // exp2 arg <= 0 always
        __syncthreads();                       // all reads done before re-zero
        for (int idx = t; idx < NC * ST; idx += NTHREADS) T1L[idx] = 0.f;
        if (t < NC) RsumL[t] = 0.f;
        __syncthreads();

        float t1[16];
        #pragma unroll
        for (int d = 0; d < 16; ++d) t1[d] = 0.f;
        float rsum = 0.f;

        auto stepE = [&](float (&wa)[16], int i) {
            float ma[16];
            const float4* mp4 = (const float4*)(MpL + (i << 4));
            ((float4*)ma)[0] = mp4[0]; ((float4*)ma)[1] = mp4[1];
            ((float4*)ma)[2] = mp4[2]; ((float4*)ma)[3] = mp4[3];
            float a_i = apL[i];
            float v[16];
            #pragma unroll
            for (int p = 0; p < 4; ++p)
                #pragma unroll
                for (int r = 0; r < 4; ++r) {
                    float acc = ma[p * 4 + 0] * wa[0 * 4 + r];
                    acc = fmaf(ma[p * 4 + 1], wa[1 * 4 + r], acc);
                    acc = fmaf(ma[p * 4 + 2], wa[2 * 4 + r], acc);
                    acc = fmaf(ma[p * 4 + 3], wa[3 * 4 + r], acc);
                    v[p * 4 + r] = acc;
                }
            // two 8-deep partial chains instead of one 16-deep
            float lpa = 0.f, lpb = 0.f;
            #pragma unroll
            for (int d = 0; d < 8; ++d) {
                float df = v[d] - Mreg[d];
                lpa = fmaf(-df * df, i2[d], lpa);
            }
            #pragma unroll
            for (int d = 8; d < 16; ++d) {
                float df = v[d] - Mreg[d];
                lpb = fmaf(-df * df, i2[d], lpb);
            }
            float ex = exp2f(Kc2 + lpa + lpb); // <= 1; denom >= e^-8: safe
            // softmax denominator over the 32 caps of this half-wave:
            // DPP row sum (lane bits 0-3) + one cross-row shfl (bit 4)
            float ssum = row_sum16(ex);
            ssum += __shfl_xor(ssum, 16);
            float rw = ex * rcp_fast(ssum) * a_i;
            rsum += rw;
            #pragma unroll
            for (int d = 0; d < 16; ++d) t1[d] = fmaf(rw, v[d], t1[d]);
        };

        float waA[16], waB[16];
        loadW(waA, iBase);
        for (int j = 0; j < IPT; j += 2) {
            loadW(waB, iBase + j + 1);
            stepE(waA, iBase + j);
            if (j + 2 < IPT) loadW(waA, iBase + j + 2);
            stepE(waB, iBase + j + 1);
        }

        rsum += __shfl_xor(rsum, 32);
        #pragma unroll
        for (int d = 0; d < 16; ++d) t1[d] += __shfl_xor(t1[d], 32);
        if ((t & 32) == 0) {
            atomicAdd(&RsumL[c], rsum);
            #pragma unroll
            for (int d = 0; d < 16; ++d) atomicAdd(&T1L[c * ST + d], t1[d]);
        }
        __syncthreads();
        statsA();
        __syncthreads();
        statsB(1.0f + (float)it);   // inv_temp = 1 + it
        __syncthreads();
    }

    // ---- epilogue: out[b,ho,wo,c,0:16]=M, out[...,16]=sigmoid(a_j) ----
    // output stride per capsule is 17 == ST, so ML indexes line up directly.
    for (int idx = t; idx < NC * 17; idx += NTHREADS) {
        int cc = idx / 17;
        int e = idx - cc * 17;
        float val = (e < 16) ? ML[idx] : aoutL[cc];
        out[(size_t)bid * (NC * 17) + idx] = val;
    }
}

extern "C" void kernel_launch(void* const* d_in, const int* in_sizes, int n_in,
                              void* d_out, int out_size, void* d_ws, size_t ws_size,
                              hipStream_t stream) {
    const float* x  = (const float*)d_in[0];
    const float* W  = (const float*)d_in[1];
    const float* bv = (const float*)d_in[2];
    const float* ba = (const float*)d_in[3];
    float* out = (float*)d_out;
    // grid = B*Ho*Wo = 2*12*12 = 288 positions, one block each
    caps_em_kernel<<<288, NTHREADS, 0, stream>>>(x, W, bv, ba, out);
}

// Round 9
// 169.801 us; speedup vs baseline: 1.9436x; 1.0582x over previous
//
#include <hip/hip_runtime.h>
#include <math.h>

// ConvolutionalCapsule with EM routing, fully fused. Round-9 decomposition:
// grid 144, block 1024 = TWO independent 512-thread units, each processing
// one output position (pos = bid*2 + H). Rationale (R0-R8 occupancy
// arithmetic): the machine runs 1 workgroup/CU here regardless of resources
// (R4/R5: LDS 31KB vs 82KB identical; measured OccupancyPercent always =
// the 2-round average, never the co-residency value), so a 288-block grid
// executes as 256 + 32 => the 32-block tail doubles kernel time. 144 blocks
// <= 256 CUs => ONE round. Per-unit body is R7 verbatim (W-prefetch of R8
// reverted: measured null, costs 12 regs).
// Known cost: 1024-thr VGPR cap is 64 on this toolchain (R3-R5: immovable
// via launch_bounds/waves_per_eu/LDS-pad) vs ~72 demand => ~8-reg spill,
// calibrated ~+15us (R3 vs R6: 26-over => +46us). Tail removal ~-64us.
// Key algebraic facts (proven R3-R8):
//  - var = UNWEIGHTED sum_i (v-M)^2 => S1,S2 iteration-invariant.
//  - Kmax = max_c Kc shift => exp2 args <= 0, denom >= e^-8, no per-i max.
//  - cost = rsum * (16*beta_v + sum_d log(stdv+eps)).
//  - DPP row reduce (R7, +8us); parallel statsA/statsB (R6).
// Unit thread map: c = u&31, isub = u>>5 (0..15), i = isub*18 + j.

#define EPSF 1e-7f
#define KKI 288
#define NC 32
#define NTHREADS 1024
#define UNIT 512
#define IPT 18          // KKI / 16 half-waves per unit
#define ST 17           // padded stride: (17c+d)%32 bijective over c
#define L2E 1.4426950408889634f

__device__ __forceinline__ float rcp_fast(float v) { return __builtin_amdgcn_rcpf(v); }

// DPP-based cross-lane (VALU pipe; proven R7)
template <int CTRL>
__device__ __forceinline__ float dpp_mov_f(float x) {
    return __int_as_float(__builtin_amdgcn_update_dpp(
        0, __float_as_int(x), CTRL, 0xF, 0xF, true));
}
__device__ __forceinline__ float row_sum16(float x) {
    x += dpp_mov_f<0xB1>(x);    // quad_perm xor1
    x += dpp_mov_f<0x4E>(x);    // quad_perm xor2
    x += dpp_mov_f<0x124>(x);   // row_ror:4
    x += dpp_mov_f<0x128>(x);   // row_ror:8
    return x;
}
__device__ __forceinline__ float row_max16(float x) {
    x = fmaxf(x, dpp_mov_f<0xB1>(x));
    x = fmaxf(x, dpp_mov_f<0x4E>(x));
    x = fmaxf(x, dpp_mov_f<0x124>(x));
    x = fmaxf(x, dpp_mov_f<0x128>(x));
    return x;
}

__global__ __launch_bounds__(NTHREADS)
void caps_em_kernel(const float* __restrict__ x, const float* __restrict__ Wg,
                    const float* __restrict__ beta_v, const float* __restrict__ beta_a,
                    float* __restrict__ out)
{
    // per-unit LDS (H = 0/1). Total ~62KB.
    __shared__ float MpL[2][KKI * 16];
    __shared__ float apL[2][KKI];
    __shared__ float T1L[2][NC * ST];
    __shared__ float S1L[2][NC * ST];
    __shared__ float S2L[2][NC * ST];
    __shared__ float ML[2][NC * ST];
    __shared__ float I2L[2][NC * ST];   // 0.5/var * log2e (pre-scaled)
    __shared__ float RsumL[2][NC];
    __shared__ float constL[2][NC];
    __shared__ float slogL[2][NC];
    __shared__ float costL[2][NC];
    __shared__ float aoutL[2][NC];
    __shared__ float KmaxL[2];

    const int t = threadIdx.x;
    const int H = t >> 9;                 // unit id (waves never straddle)
    const int u = t & 511;                // unit-local thread id
    const int pos = blockIdx.x * 2 + H;   // 0..287 = b*144 + ho*12 + wo
    const int b = pos / 144;
    const int rem = pos - b * 144;
    const int ho = rem / 12;
    const int wo = rem - ho * 12;

    const int c = u & 31;
    const int isub = u >> 5;              // 0..15
    const int iBase = isub * IPT;

    // ---- stage patch tile for this unit's position ----
    for (int idx = u; idx < KKI * 17; idx += UNIT) {
        int i = idx / 17;
        int e = idx - i * 17;
        int p = i >> 5, cin = i & 31;
        int di = p / 3, dj = p - di * 3;
        float vx = x[(((b * 14 + (ho + di)) * 14 + (wo + dj)) * 32 + cin) * 17 + e];
        if (e < 16) MpL[H][i * 16 + e] = vx; else apL[H][i] = vx;
    }
    for (int idx = u; idx < NC * ST; idx += UNIT) { T1L[H][idx] = 0.f; S1L[H][idx] = 0.f; S2L[H][idx] = 0.f; }
    if (u < NC) RsumL[H][u] = 0.f;
    __syncthreads();

    // stats A: all 512 unit-threads, one per (cc = u>>4, d = u&15);
    // d = lane bits 0-3 => pure-DPP row sum for slog.
    auto statsA = [&]() {
        const int cc = u >> 4, d = u & 15;
        float rsum = RsumL[H][cc];
        float m = T1L[H][cc * ST + d] * rcp_fast(rsum);
        float var = S2L[H][cc * ST + d] - 2.f * m * S1L[H][cc * ST + d] + 288.f * m * m;
        var = fmaxf(var, 0.f);
        float lg = logf(sqrtf(var) + EPSF);
        ML[H][cc * ST + d] = m;
        I2L[H][cc * ST + d] = 0.5f * L2E * rcp_fast(var);
        float sl = row_sum16(lg);
        if (d == 0) {
            slogL[H][cc] = sl;
            costL[H][cc] = rsum * (16.f * beta_v[cc] + sl);
        }
    };
    // stats B: cross-capsule mean/std + activation + Kmax (32 unit-threads:
    // lanes 0-31 of wave 0 (H=0) / wave 8 (H=1)).
    auto statsB = [&](float inv_temp) {
        if (u < 32) {
            float cost = costL[H][u];
            float csum = row_sum16(cost); csum += __shfl_xor(csum, 16);
            float c_mean = csum * 0.03125f;
            float diff = cost - c_mean;
            float dsq = row_sum16(diff * diff); dsq += __shfl_xor(dsq, 16);
            float c_stdv = sqrtf(dsq * 0.03125f);
            float a_cost = beta_a[u] + (c_mean - cost) * rcp_fast(c_stdv + EPSF);
            float a_j = 1.f / (1.f + expf(-inv_temp * a_cost));
            float kc = logf(a_j + EPSF) - slogL[H][u];
            constL[H][u] = kc;
            aoutL[H][u] = 1.f / (1.f + expf(-a_j));
            float km = row_max16(kc); km = fmaxf(km, __shfl_xor(km, 16));
            if (u == 0) KmaxL[H] = km;
        }
    };

    // ---- pass 0: R uniform 1/32 -> Rw = ap/32; also build S1,S2 ----
    {
        float t1[16], s1[16], s2[16];
        #pragma unroll
        for (int d = 0; d < 16; ++d) { t1[d] = 0.f; s1[d] = 0.f; s2[d] = 0.f; }
        float rsum = 0.f;
        for (int j = 0; j < IPT; ++j) {
            const int i = iBase + j;
            float wa[16], ma[16];
            const float4* w4 = (const float4*)(Wg + ((size_t)((i << 5) + c) << 4));
            ((float4*)wa)[0] = w4[0]; ((float4*)wa)[1] = w4[1];
            ((float4*)wa)[2] = w4[2]; ((float4*)wa)[3] = w4[3];
            const float4* mp4 = (const float4*)(&MpL[H][i << 4]);
            ((float4*)ma)[0] = mp4[0]; ((float4*)ma)[1] = mp4[1];
            ((float4*)ma)[2] = mp4[2]; ((float4*)ma)[3] = mp4[3];
            float rw = apL[H][i] * 0.03125f;
            rsum += rw;
            #pragma unroll
            for (int p = 0; p < 4; ++p)
                #pragma unroll
                for (int r = 0; r < 4; ++r) {
                    float acc = ma[p * 4 + 0] * wa[0 * 4 + r];
                    acc = fmaf(ma[p * 4 + 1], wa[1 * 4 + r], acc);
                    acc = fmaf(ma[p * 4 + 2], wa[2 * 4 + r], acc);
                    acc = fmaf(ma[p * 4 + 3], wa[3 * 4 + r], acc);
                    const int d = p * 4 + r;
                    t1[d] = fmaf(rw, acc, t1[d]);
                    s1[d] += acc;
                    s2[d] = fmaf(acc, acc, s2[d]);
                }
        }
        // combine partner half-waves (lane^32 shares c), then 32 lanes atomic
        rsum += __shfl_xor(rsum, 32);
        #pragma unroll
        for (int d = 0; d < 16; ++d) {
            t1[d] += __shfl_xor(t1[d], 32);
            s1[d] += __shfl_xor(s1[d], 32);
            s2[d] += __shfl_xor(s2[d], 32);
        }
        if ((u & 32) == 0) {
            atomicAdd(&RsumL[H][c], rsum);
            #pragma unroll
            for (int d = 0; d < 16; ++d) {
                atomicAdd(&T1L[H][c * ST + d], t1[d]);
                atomicAdd(&S1L[H][c * ST + d], s1[d]);
                atomicAdd(&S2L[H][c * ST + d], s2[d]);
            }
        }
        __syncthreads();
        statsA();
        __syncthreads();
        statsB(1.0f);   // it = 0
        __syncthreads();
    }

    // ---- passes 1,2: fused E-step (softmax over c, in-register) + M-step ----
    for (int it = 1; it < 3; ++it) {
        float Mreg[16], i2[16];
        #pragma unroll
        for (int d = 0; d < 16; ++d) {
            Mreg[d] = ML[H][c * ST + d];
            i2[d]   = I2L[H][c * ST + d];      // already log2-space scaled
        }
        float Kc2 = (constL[H][c] - KmaxL[H]) * L2E;  // exp2 arg <= 0 always
        __syncthreads();                       // all reads done before re-zero
        for (int idx = u; idx < NC * ST; idx += UNIT) T1L[H][idx] = 0.f;
        if (u < NC) RsumL[H][u] = 0.f;
        __syncthreads();

        float t1[16];
        #pragma unroll
        for (int d = 0; d < 16; ++d) t1[d] = 0.f;
        float rsum = 0.f;
        for (int j = 0; j < IPT; ++j) {
            const int i = iBase + j;
            float wa[16], ma[16];
            const float4* w4 = (const float4*)(Wg + ((size_t)((i << 5) + c) << 4));
            ((float4*)wa)[0] = w4[0]; ((float4*)wa)[1] = w4[1];
            ((float4*)wa)[2] = w4[2]; ((float4*)wa)[3] = w4[3];
            const float4* mp4 = (const float4*)(&MpL[H][i << 4]);
            ((float4*)ma)[0] = mp4[0]; ((float4*)ma)[1] = mp4[1];
            ((float4*)ma)[2] = mp4[2]; ((float4*)ma)[3] = mp4[3];
            float a_i = apL[H][i];
            float v[16];
            #pragma unroll
            for (int p = 0; p < 4; ++p)
                #pragma unroll
                for (int r = 0; r < 4; ++r) {
                    float acc = ma[p * 4 + 0] * wa[0 * 4 + r];
                    acc = fmaf(ma[p * 4 + 1], wa[1 * 4 + r], acc);
                    acc = fmaf(ma[p * 4 + 2], wa[2 * 4 + r], acc);
                    acc = fmaf(ma[p * 4 + 3], wa[3 * 4 + r], acc);
                    v[p * 4 + r] = acc;
                }
            // two 8-deep partial chains (R8, passed)
            float lpa = 0.f, lpb = 0.f;
            #pragma unroll
            for (int d = 0; d < 8; ++d) {
                float df = v[d] - Mreg[d];
                lpa = fmaf(-df * df, i2[d], lpa);
            }
            #pragma unroll
            for (int d = 8; d < 16; ++d) {
                float df = v[d] - Mreg[d];
                lpb = fmaf(-df * df, i2[d], lpb);
            }
            float ex = exp2f(Kc2 + lpa + lpb); // <= 1; denom >= e^-8: safe
            // softmax denominator over the 32 caps of this half-wave:
            // DPP row sum (lane bits 0-3) + one cross-row shfl (bit 4)
            float ssum = row_sum16(ex);
            ssum += __shfl_xor(ssum, 16);
            float rw = ex * rcp_fast(ssum) * a_i;
            rsum += rw;
            #pragma unroll
            for (int d = 0; d < 16; ++d) t1[d] = fmaf(rw, v[d], t1[d]);
        }
        rsum += __shfl_xor(rsum, 32);
        #pragma unroll
        for (int d = 0; d < 16; ++d) t1[d] += __shfl_xor(t1[d], 32);
        if ((u & 32) == 0) {
            atomicAdd(&RsumL[H][c], rsum);
            #pragma unroll
            for (int d = 0; d < 16; ++d) atomicAdd(&T1L[H][c * ST + d], t1[d]);
        }
        __syncthreads();
        statsA();
        __syncthreads();
        statsB(1.0f + (float)it);   // inv_temp = 1 + it
        __syncthreads();
    }

    // ---- epilogue: out[pos,c,0:16]=M, out[pos,c,16]=sigmoid(a_j) ----
    // output stride per capsule is 17 == ST, so ML indexes line up directly.
    for (int idx = u; idx < NC * 17; idx += UNIT) {
        int cc = idx / 17;
        int e = idx - cc * 17;
        float val = (e < 16) ? ML[H][idx] : aoutL[H][cc];
        out[(size_t)pos * (NC * 17) + idx] = val;
    }
}

extern "C" void kernel_launch(void* const* d_in, const int* in_sizes, int n_in,
                              void* d_out, int out_size, void* d_ws, size_t ws_size,
                              hipStream_t stream) {
    const float* x  = (const float*)d_in[0];
    const float* W  = (const float*)d_in[1];
    const float* bv = (const float*)d_in[2];
    const float* ba = (const float*)d_in[3];
    float* out = (float*)d_out;
    // 288 positions, 2 per block => grid 144 <= 256 CUs: single dispatch round
    caps_em_kernel<<<144, NTHREADS, 0, stream>>>(x, W, bv, ba, out);
}